// Round 3
// baseline (1078.372 us; speedup 1.0000x reference)
//
#include <hip/hip_runtime.h>
#include <hip/hip_bf16.h>

// PSN: quantize latents (16384 x 256) f32 against codebook (8192 x 256) f32.
// Outputs (flat f32): st[16384*256], loss[1], inds_noisy[16384] (as float).
//
// Pipeline: prep(split f32 -> bf16 hi/lo) -> wnorm -> MFMA approx argmin with
// top-2 tracking -> flag near-ties (gap < EPS) -> exact f32 rerank of flagged
// rows -> finalize (st, loss, indices).

namespace {
constexpr int N_ROWS  = 16384;
constexpr int K_CODES = 8192;
constexpr int C_DIM   = 256;
constexpr float EPS_GAP = 0.0625f;   // >> 2x worst-case bf16-split error (~1e-3)
}

typedef __attribute__((ext_vector_type(8)))  short bf16x8;
typedef __attribute__((ext_vector_type(16))) float f32x16;

__device__ __forceinline__ unsigned f2key(float f) {
    unsigned u = __float_as_uint(f);
    return (u & 0x80000000u) ? ~u : (u | 0x80000000u);
}
__device__ __forceinline__ float key2f(unsigned k) {
    unsigned u = (k & 0x80000000u) ? (k ^ 0x80000000u) : ~k;
    return __uint_as_float(u);
}
__device__ __forceinline__ unsigned short f2bf(float x) {
    unsigned u = __float_as_uint(x);
    unsigned r = u + 0x7fffu + ((u >> 16) & 1u);   // RNE
    return (unsigned short)(r >> 16);
}

// ---------------- prep: f32 -> (bf16 hi, bf16 lo) ----------------
extern "C" __global__ void prep_kernel(const float* __restrict__ src,
                                       unsigned short* __restrict__ hi,
                                       unsigned short* __restrict__ lo) {
    const int i = (blockIdx.x * 256 + threadIdx.x) * 8;
    float4 a = *(const float4*)&src[i];
    float4 b = *(const float4*)&src[i + 4];
    float v[8] = {a.x, a.y, a.z, a.w, b.x, b.y, b.z, b.w};
    unsigned short h[8], l[8];
    #pragma unroll
    for (int j = 0; j < 8; ++j) {
        h[j] = f2bf(v[j]);
        float hf = __uint_as_float((unsigned)h[j] << 16);
        l[j] = f2bf(v[j] - hf);
    }
    ushort4 h0 = {h[0], h[1], h[2], h[3]}, h1 = {h[4], h[5], h[6], h[7]};
    ushort4 l0 = {l[0], l[1], l[2], l[3]}, l1 = {l[4], l[5], l[6], l[7]};
    *(ushort4*)&hi[i] = h0;  *(ushort4*)&hi[i + 4] = h1;
    *(ushort4*)&lo[i] = l0;  *(ushort4*)&lo[i + 4] = l1;
}

// ---------------- wnorm ----------------
extern "C" __global__ void wnorm_kernel(const float* __restrict__ cbk,
                                        float* __restrict__ wnorm) {
    const int k = blockIdx.x * 4 + (threadIdx.x >> 6);
    const int lane = threadIdx.x & 63;
    float4 v = reinterpret_cast<const float4*>(cbk + (size_t)k * C_DIM)[lane];
    float s = v.x * v.x + v.y * v.y + v.z * v.z + v.w * v.w;
    #pragma unroll
    for (int m = 32; m; m >>= 1) s += __shfl_xor(s, m, 64);
    if (lane == 0) wnorm[k] = s;
}

// ---------------- pass1: MFMA approx argmin, top-2 per row ----------------
// grid 1024: rb = bid&127 (row block of 128), cs = bid>>7 (code split of 1024)
// block 256 thr = 4 waves (2 row x 2 col), wave tile 64x64, mfma 32x32x16.
extern "C" __global__ void __launch_bounds__(256, 2)
pass1_kernel(const unsigned short* __restrict__ xh_g,
             const unsigned short* __restrict__ xl_g,
             const unsigned short* __restrict__ wh_g,
             const unsigned short* __restrict__ wl_g,
             const float* __restrict__ wnorm,
             unsigned long long* __restrict__ keys,
             unsigned* __restrict__ keys2) {
    // 40 bf16 (80 B) row stride
    __shared__ __align__(16) unsigned short XH[128 * 40], XL[128 * 40];
    __shared__ __align__(16) unsigned short WH[128 * 40], WL[128 * 40];
    const int tid = threadIdx.x;
    const int lane = tid & 63;
    const int wid = tid >> 6;
    const int wr = wid >> 1, wc = wid & 1;
    const int h = lane >> 5;
    const int l31 = lane & 31;
    const int rb = blockIdx.x & 127, cs = blockIdx.x >> 7;
    const int r0 = rb * 128, cbase = cs * 1024;

    float bv[2][16];  unsigned bi[2][16];  float sv[2][16];
    #pragma unroll
    for (int tm = 0; tm < 2; ++tm)
        #pragma unroll
        for (int r = 0; r < 16; ++r) { bv[tm][r] = 3.4e38f; sv[tm][r] = 3.4e38f; bi[tm][r] = 0; }

    const int c0r = tid >> 2, cg = tid & 3;     // staging: rows c0r and c0r+64, chunk cg

    for (int ct = 0; ct < 8; ++ct) {
        const int cb = cbase + ct * 128;
        f32x16 acc[2][2];
        #pragma unroll
        for (int tm = 0; tm < 2; ++tm)
            #pragma unroll
            for (int tn = 0; tn < 2; ++tn)
                #pragma unroll
                for (int e = 0; e < 16; ++e) acc[tm][tn][e] = 0.0f;

        // FIX (r2 bug): wave-column offset wc*64 must appear in the code index
        // and wnorm lookup, matching the B-fragment LDS rows (wc*64 + l31).
        const float wnA = wnorm[cb + wc * 64 + l31];
        const float wnB = wnorm[cb + wc * 64 + 32 + l31];
        const unsigned cA = cb + wc * 64 + l31;
        const unsigned cB = cA + 32;

        for (int kc = 0; kc < 8; ++kc) {
            __syncthreads();
            {
                const size_t xo0 = (size_t)(r0 + c0r) * 256 + kc * 32 + cg * 8;
                const size_t xo1 = (size_t)(r0 + c0r + 64) * 256 + kc * 32 + cg * 8;
                const size_t wo0 = (size_t)(cb + c0r) * 256 + kc * 32 + cg * 8;
                const size_t wo1 = (size_t)(cb + c0r + 64) * 256 + kc * 32 + cg * 8;
                uint4 a0 = *(const uint4*)(xh_g + xo0);
                uint4 a1 = *(const uint4*)(xh_g + xo1);
                uint4 a2 = *(const uint4*)(xl_g + xo0);
                uint4 a3 = *(const uint4*)(xl_g + xo1);
                uint4 b0 = *(const uint4*)(wh_g + wo0);
                uint4 b1 = *(const uint4*)(wh_g + wo1);
                uint4 b2 = *(const uint4*)(wl_g + wo0);
                uint4 b3 = *(const uint4*)(wl_g + wo1);
                const int s0 = c0r * 40 + cg * 8, s1 = (c0r + 64) * 40 + cg * 8;
                *(uint4*)&XH[s0] = a0;  *(uint4*)&XH[s1] = a1;
                *(uint4*)&XL[s0] = a2;  *(uint4*)&XL[s1] = a3;
                *(uint4*)&WH[s0] = b0;  *(uint4*)&WH[s1] = b1;
                *(uint4*)&WL[s0] = b2;  *(uint4*)&WL[s1] = b3;
            }
            __syncthreads();
            #pragma unroll
            for (int kk = 0; kk < 2; ++kk) {
                const int g8 = (kk * 2 + h) * 8;
                const int ra0 = (wr * 64 + l31) * 40 + g8;
                const int ra1 = (wr * 64 + 32 + l31) * 40 + g8;
                const int rb0 = (wc * 64 + l31) * 40 + g8;
                const int rb1 = (wc * 64 + 32 + l31) * 40 + g8;
                bf16x8 a0h = *(const bf16x8*)&XH[ra0];
                bf16x8 a1h = *(const bf16x8*)&XH[ra1];
                bf16x8 a0l = *(const bf16x8*)&XL[ra0];
                bf16x8 a1l = *(const bf16x8*)&XL[ra1];
                bf16x8 b0h = *(const bf16x8*)&WH[rb0];
                bf16x8 b1h = *(const bf16x8*)&WH[rb1];
                bf16x8 b0l = *(const bf16x8*)&WL[rb0];
                bf16x8 b1l = *(const bf16x8*)&WL[rb1];
                acc[0][0] = __builtin_amdgcn_mfma_f32_32x32x16_bf16(a0h, b0h, acc[0][0], 0, 0, 0);
                acc[0][1] = __builtin_amdgcn_mfma_f32_32x32x16_bf16(a0h, b1h, acc[0][1], 0, 0, 0);
                acc[1][0] = __builtin_amdgcn_mfma_f32_32x32x16_bf16(a1h, b0h, acc[1][0], 0, 0, 0);
                acc[1][1] = __builtin_amdgcn_mfma_f32_32x32x16_bf16(a1h, b1h, acc[1][1], 0, 0, 0);
                acc[0][0] = __builtin_amdgcn_mfma_f32_32x32x16_bf16(a0h, b0l, acc[0][0], 0, 0, 0);
                acc[0][1] = __builtin_amdgcn_mfma_f32_32x32x16_bf16(a0h, b1l, acc[0][1], 0, 0, 0);
                acc[1][0] = __builtin_amdgcn_mfma_f32_32x32x16_bf16(a1h, b0l, acc[1][0], 0, 0, 0);
                acc[1][1] = __builtin_amdgcn_mfma_f32_32x32x16_bf16(a1h, b1l, acc[1][1], 0, 0, 0);
                acc[0][0] = __builtin_amdgcn_mfma_f32_32x32x16_bf16(a0l, b0h, acc[0][0], 0, 0, 0);
                acc[0][1] = __builtin_amdgcn_mfma_f32_32x32x16_bf16(a0l, b1h, acc[0][1], 0, 0, 0);
                acc[1][0] = __builtin_amdgcn_mfma_f32_32x32x16_bf16(a1l, b0h, acc[1][0], 0, 0, 0);
                acc[1][1] = __builtin_amdgcn_mfma_f32_32x32x16_bf16(a1l, b1h, acc[1][1], 0, 0, 0);
            }
        }
        // epilogue: running (best, idx, second) per row-slot; codes ascend -> first-index ties
        #pragma unroll
        for (int tm = 0; tm < 2; ++tm)
            #pragma unroll
            for (int r = 0; r < 16; ++r) {
                float s0 = fmaf(-2.0f, acc[tm][0][r], wnA);
                bool c0 = s0 < bv[tm][r];
                sv[tm][r] = fminf(sv[tm][r], c0 ? bv[tm][r] : s0);
                bv[tm][r] = c0 ? s0 : bv[tm][r];
                bi[tm][r] = c0 ? cA : bi[tm][r];
                float s1 = fmaf(-2.0f, acc[tm][1][r], wnB);
                bool c1 = s1 < bv[tm][r];
                sv[tm][r] = fminf(sv[tm][r], c1 ? bv[tm][r] : s1);
                bv[tm][r] = c1 ? s1 : bv[tm][r];
                bi[tm][r] = c1 ? cB : bi[tm][r];
            }
    }
    // merge across the 32 lanes sharing each row set, then lock-free global top-2
    #pragma unroll
    for (int tm = 0; tm < 2; ++tm)
        #pragma unroll
        for (int r = 0; r < 16; ++r) {
            unsigned long long key =
                ((unsigned long long)f2key(bv[tm][r]) << 32) | bi[tm][r];
            unsigned sk = f2key(sv[tm][r]);
            #pragma unroll
            for (int m = 1; m < 32; m <<= 1) {
                unsigned long long ko = __shfl_xor(key, m, 64);
                unsigned sko = __shfl_xor(sk, m, 64);
                unsigned long long loser = key < ko ? ko : key;
                sk = min(min(sk, sko), (unsigned)(loser >> 32));
                key = key < ko ? key : ko;
            }
            if (l31 == 0) {
                const int grow = r0 + wr * 64 + tm * 32 + (r & 3) + 8 * (r >> 2) + 4 * h;
                unsigned long long old = atomicMin(&keys[grow], key);
                if (old != ~0ull) {
                    unsigned long long loser = old < key ? key : old;
                    atomicMin(&keys2[grow], (unsigned)(loser >> 32));
                }
                atomicMin(&keys2[grow], sk);
            }
        }
}

// ---------------- flag near-ties ----------------
extern "C" __global__ void flag_kernel(unsigned long long* __restrict__ keys,
                                       const unsigned* __restrict__ keys2,
                                       int* __restrict__ list, int* __restrict__ count) {
    const int row = blockIdx.x * 256 + threadIdx.x;
    unsigned long long k = keys[row];
    float b = key2f((unsigned)(k >> 32));
    float s = key2f(keys2[row]);
    if (s - b < EPS_GAP) {
        int p = atomicAdd(count, 1);
        list[p] = row;
        keys[row] = ~0ull;   // rerank rebuilds from scratch
    }
}

// ---------------- exact f32 rerank of flagged rows ----------------
extern "C" __global__ void rerank_kernel(const float* __restrict__ lat,
                                         const float* __restrict__ cbk,
                                         const float* __restrict__ wnorm,
                                         const int* __restrict__ list,
                                         const int* __restrict__ count,
                                         unsigned long long* __restrict__ keys) {
    const int slot = threadIdx.x >> 6, lane = threadIdx.x & 63;
    const int code = blockIdx.x * 4 + slot;
    const float4 wv = *(const float4*)&cbk[(size_t)code * C_DIM + lane * 4];
    const float wn = wnorm[code];
    const int n = *count;
    for (int i = 0; i < n; ++i) {
        const int row = list[i];
        float4 xv = *(const float4*)&lat[(size_t)row * C_DIM + lane * 4];
        float d = xv.x * wv.x;
        d = fmaf(xv.y, wv.y, d);
        d = fmaf(xv.z, wv.z, d);
        d = fmaf(xv.w, wv.w, d);
        #pragma unroll
        for (int m = 1; m < 64; m <<= 1) d += __shfl_xor(d, m, 64);
        if (lane == 0) {
            float s = fmaf(-2.0f, d, wn);
            unsigned long long key =
                ((unsigned long long)f2key(s) << 32) | (unsigned)code;
            atomicMin(&keys[row], key);
        }
    }
}

// ---------------- finalize ----------------
extern "C" __global__ void finalize_kernel(const float* __restrict__ lat,
                                           const float* __restrict__ cbk,
                                           const float* __restrict__ noise,
                                           const unsigned long long* __restrict__ keys,
                                           float* __restrict__ out) {
    const int row = blockIdx.x;
    const int c = threadIdx.x;
    const unsigned long long p = keys[row];
    const int id = (int)(unsigned)(p & 0xFFFFFFFFull);
    const int off = (int)rintf(noise[row] * 0.5f);
    int idn = id + off;
    idn = idn < 0 ? 0 : (idn > K_CODES - 1 ? K_CODES - 1 : idn);
    const float x  = lat[(size_t)row * C_DIM + c];
    const float qd = cbk[(size_t)id  * C_DIM + c];
    const float qn = cbk[(size_t)idn * C_DIM + c];
    out[(size_t)row * C_DIM + c] = x + (qn - x);
    const float d1 = x - qd;
    const float d2 = qn - x;
    float t = (0.25f * d1 * d1 + d2 * d2) * (1.0f / 4194304.0f);
    #pragma unroll
    for (int m = 32; m; m >>= 1) t += __shfl_xor(t, m, 64);
    __shared__ float red[4];
    if ((c & 63) == 0) red[c >> 6] = t;
    __syncthreads();
    if (c == 0) {
        atomicAdd(out + (size_t)N_ROWS * C_DIM, red[0] + red[1] + red[2] + red[3]);
        out[(size_t)N_ROWS * C_DIM + 1 + row] = (float)idn;
    }
}

extern "C" void kernel_launch(void* const* d_in, const int* in_sizes, int n_in,
                              void* d_out, int out_size, void* d_ws, size_t ws_size,
                              hipStream_t stream) {
    const float* lat   = (const float*)d_in[0];
    const float* cbk   = (const float*)d_in[1];
    const float* noise = (const float*)d_in[2];
    float* out = (float*)d_out;

    char* ws = (char*)d_ws;
    unsigned short* xh = (unsigned short*)(ws);                    //  8 MB
    unsigned short* xl = (unsigned short*)(ws + 8388608);          //  8 MB
    unsigned short* wh = (unsigned short*)(ws + 16777216);         //  4 MB
    unsigned short* wl = (unsigned short*)(ws + 20971520);         //  4 MB
    float* wnorm       = (float*)(ws + 25165824);                  // 32 KB
    unsigned long long* keys = (unsigned long long*)(ws + 25198592); // 128 KB
    unsigned* keys2    = (unsigned*)(ws + 25329664);               // 64 KB
    int* list          = (int*)(ws + 25395200);                    // 64 KB
    int* count         = (int*)(ws + 25460736);

    hipMemsetAsync(keys,  0xFF, (size_t)N_ROWS * 8, stream);
    hipMemsetAsync(keys2, 0xFF, (size_t)N_ROWS * 4, stream);
    hipMemsetAsync(count, 0, sizeof(int), stream);
    hipMemsetAsync(out + (size_t)N_ROWS * C_DIM, 0, sizeof(float), stream);

    prep_kernel<<<2048, 256, 0, stream>>>(lat, xh, xl);
    prep_kernel<<<1024, 256, 0, stream>>>(cbk, wh, wl);
    wnorm_kernel<<<K_CODES / 4, 256, 0, stream>>>(cbk, wnorm);
    pass1_kernel<<<1024, 256, 0, stream>>>(xh, xl, wh, wl, wnorm, keys, keys2);
    flag_kernel<<<N_ROWS / 256, 256, 0, stream>>>(keys, keys2, list, count);
    rerank_kernel<<<K_CODES / 4, 256, 0, stream>>>(lat, cbk, wnorm, list, count, keys);
    finalize_kernel<<<N_ROWS, 256, 0, stream>>>(lat, cbk, noise, keys, out);
}

// Round 4
// 712.978 us; speedup vs baseline: 1.5125x; 1.5125x over previous
//
#include <hip/hip_runtime.h>
#include <hip/hip_bf16.h>

// PSN: quantize latents (16384 x 256) f32 against codebook (8192 x 256) f32.
// Outputs (flat f32): st[16384*256], loss[1], inds_noisy[16384] (as float).
//
// Pipeline: prep(split f32 -> bf16 hi/lo) -> wnorm -> MFMA approx argmin with
// top-2 tracking -> flag near-ties (gap < EPS) -> exact f32 rerank of flagged
// rows -> finalize (st, loss, indices).

namespace {
constexpr int N_ROWS  = 16384;
constexpr int K_CODES = 8192;
constexpr int C_DIM   = 256;
// r3 post-mortem: gap density near 0 is high (~13k rows/unit); 0.0625 flagged
// ~1-3k rows and rerank dominated (660us). Split error sigma ~1.5e-4, tail
// ~1e-3 -> 0.008 keeps >4x margin, cuts flags ~8x.
constexpr float EPS_GAP = 0.008f;
}

typedef __attribute__((ext_vector_type(8)))  short bf16x8;
typedef __attribute__((ext_vector_type(16))) float f32x16;

__device__ __forceinline__ unsigned f2key(float f) {
    unsigned u = __float_as_uint(f);
    return (u & 0x80000000u) ? ~u : (u | 0x80000000u);
}
__device__ __forceinline__ float key2f(unsigned k) {
    unsigned u = (k & 0x80000000u) ? (k ^ 0x80000000u) : ~k;
    return __uint_as_float(u);
}
__device__ __forceinline__ unsigned short f2bf(float x) {
    unsigned u = __float_as_uint(x);
    unsigned r = u + 0x7fffu + ((u >> 16) & 1u);   // RNE
    return (unsigned short)(r >> 16);
}

// ---------------- prep: f32 -> (bf16 hi, bf16 lo) ----------------
extern "C" __global__ void prep_kernel(const float* __restrict__ src,
                                       unsigned short* __restrict__ hi,
                                       unsigned short* __restrict__ lo) {
    const int i = (blockIdx.x * 256 + threadIdx.x) * 8;
    float4 a = *(const float4*)&src[i];
    float4 b = *(const float4*)&src[i + 4];
    float v[8] = {a.x, a.y, a.z, a.w, b.x, b.y, b.z, b.w};
    unsigned short h[8], l[8];
    #pragma unroll
    for (int j = 0; j < 8; ++j) {
        h[j] = f2bf(v[j]);
        float hf = __uint_as_float((unsigned)h[j] << 16);
        l[j] = f2bf(v[j] - hf);
    }
    ushort4 h0 = {h[0], h[1], h[2], h[3]}, h1 = {h[4], h[5], h[6], h[7]};
    ushort4 l0 = {l[0], l[1], l[2], l[3]}, l1 = {l[4], l[5], l[6], l[7]};
    *(ushort4*)&hi[i] = h0;  *(ushort4*)&hi[i + 4] = h1;
    *(ushort4*)&lo[i] = l0;  *(ushort4*)&lo[i + 4] = l1;
}

// ---------------- wnorm ----------------
extern "C" __global__ void wnorm_kernel(const float* __restrict__ cbk,
                                        float* __restrict__ wnorm) {
    const int k = blockIdx.x * 4 + (threadIdx.x >> 6);
    const int lane = threadIdx.x & 63;
    float4 v = reinterpret_cast<const float4*>(cbk + (size_t)k * C_DIM)[lane];
    float s = v.x * v.x + v.y * v.y + v.z * v.z + v.w * v.w;
    #pragma unroll
    for (int m = 32; m; m >>= 1) s += __shfl_xor(s, m, 64);
    if (lane == 0) wnorm[k] = s;
}

// ---------------- pass1: MFMA approx argmin, top-2 per row ----------------
// grid 1024: rb = bid&127 (row block of 128), cs = bid>>7 (code split of 1024)
// block 256 thr = 4 waves (2 row x 2 col), wave tile 64x64, mfma 32x32x16.
extern "C" __global__ void __launch_bounds__(256, 2)
pass1_kernel(const unsigned short* __restrict__ xh_g,
             const unsigned short* __restrict__ xl_g,
             const unsigned short* __restrict__ wh_g,
             const unsigned short* __restrict__ wl_g,
             const float* __restrict__ wnorm,
             unsigned long long* __restrict__ keys,
             unsigned* __restrict__ keys2) {
    // 40 bf16 (80 B) row stride
    __shared__ __align__(16) unsigned short XH[128 * 40], XL[128 * 40];
    __shared__ __align__(16) unsigned short WH[128 * 40], WL[128 * 40];
    const int tid = threadIdx.x;
    const int lane = tid & 63;
    const int wid = tid >> 6;
    const int wr = wid >> 1, wc = wid & 1;
    const int h = lane >> 5;
    const int l31 = lane & 31;
    const int rb = blockIdx.x & 127, cs = blockIdx.x >> 7;
    const int r0 = rb * 128, cbase = cs * 1024;

    float bv[2][16];  unsigned bi[2][16];  float sv[2][16];
    #pragma unroll
    for (int tm = 0; tm < 2; ++tm)
        #pragma unroll
        for (int r = 0; r < 16; ++r) { bv[tm][r] = 3.4e38f; sv[tm][r] = 3.4e38f; bi[tm][r] = 0; }

    const int c0r = tid >> 2, cg = tid & 3;     // staging: rows c0r and c0r+64, chunk cg

    for (int ct = 0; ct < 8; ++ct) {
        const int cb = cbase + ct * 128;
        f32x16 acc[2][2];
        #pragma unroll
        for (int tm = 0; tm < 2; ++tm)
            #pragma unroll
            for (int tn = 0; tn < 2; ++tn)
                #pragma unroll
                for (int e = 0; e < 16; ++e) acc[tm][tn][e] = 0.0f;

        const float wnA = wnorm[cb + wc * 64 + l31];
        const float wnB = wnorm[cb + wc * 64 + 32 + l31];
        const unsigned cA = cb + wc * 64 + l31;
        const unsigned cB = cA + 32;

        for (int kc = 0; kc < 8; ++kc) {
            __syncthreads();
            {
                const size_t xo0 = (size_t)(r0 + c0r) * 256 + kc * 32 + cg * 8;
                const size_t xo1 = (size_t)(r0 + c0r + 64) * 256 + kc * 32 + cg * 8;
                const size_t wo0 = (size_t)(cb + c0r) * 256 + kc * 32 + cg * 8;
                const size_t wo1 = (size_t)(cb + c0r + 64) * 256 + kc * 32 + cg * 8;
                uint4 a0 = *(const uint4*)(xh_g + xo0);
                uint4 a1 = *(const uint4*)(xh_g + xo1);
                uint4 a2 = *(const uint4*)(xl_g + xo0);
                uint4 a3 = *(const uint4*)(xl_g + xo1);
                uint4 b0 = *(const uint4*)(wh_g + wo0);
                uint4 b1 = *(const uint4*)(wh_g + wo1);
                uint4 b2 = *(const uint4*)(wl_g + wo0);
                uint4 b3 = *(const uint4*)(wl_g + wo1);
                const int s0 = c0r * 40 + cg * 8, s1 = (c0r + 64) * 40 + cg * 8;
                *(uint4*)&XH[s0] = a0;  *(uint4*)&XH[s1] = a1;
                *(uint4*)&XL[s0] = a2;  *(uint4*)&XL[s1] = a3;
                *(uint4*)&WH[s0] = b0;  *(uint4*)&WH[s1] = b1;
                *(uint4*)&WL[s0] = b2;  *(uint4*)&WL[s1] = b3;
            }
            __syncthreads();
            #pragma unroll
            for (int kk = 0; kk < 2; ++kk) {
                const int g8 = (kk * 2 + h) * 8;
                const int ra0 = (wr * 64 + l31) * 40 + g8;
                const int ra1 = (wr * 64 + 32 + l31) * 40 + g8;
                const int rb0 = (wc * 64 + l31) * 40 + g8;
                const int rb1 = (wc * 64 + 32 + l31) * 40 + g8;
                bf16x8 a0h = *(const bf16x8*)&XH[ra0];
                bf16x8 a1h = *(const bf16x8*)&XH[ra1];
                bf16x8 a0l = *(const bf16x8*)&XL[ra0];
                bf16x8 a1l = *(const bf16x8*)&XL[ra1];
                bf16x8 b0h = *(const bf16x8*)&WH[rb0];
                bf16x8 b1h = *(const bf16x8*)&WH[rb1];
                bf16x8 b0l = *(const bf16x8*)&WL[rb0];
                bf16x8 b1l = *(const bf16x8*)&WL[rb1];
                acc[0][0] = __builtin_amdgcn_mfma_f32_32x32x16_bf16(a0h, b0h, acc[0][0], 0, 0, 0);
                acc[0][1] = __builtin_amdgcn_mfma_f32_32x32x16_bf16(a0h, b1h, acc[0][1], 0, 0, 0);
                acc[1][0] = __builtin_amdgcn_mfma_f32_32x32x16_bf16(a1h, b0h, acc[1][0], 0, 0, 0);
                acc[1][1] = __builtin_amdgcn_mfma_f32_32x32x16_bf16(a1h, b1h, acc[1][1], 0, 0, 0);
                acc[0][0] = __builtin_amdgcn_mfma_f32_32x32x16_bf16(a0h, b0l, acc[0][0], 0, 0, 0);
                acc[0][1] = __builtin_amdgcn_mfma_f32_32x32x16_bf16(a0h, b1l, acc[0][1], 0, 0, 0);
                acc[1][0] = __builtin_amdgcn_mfma_f32_32x32x16_bf16(a1h, b0l, acc[1][0], 0, 0, 0);
                acc[1][1] = __builtin_amdgcn_mfma_f32_32x32x16_bf16(a1h, b1l, acc[1][1], 0, 0, 0);
                acc[0][0] = __builtin_amdgcn_mfma_f32_32x32x16_bf16(a0l, b0h, acc[0][0], 0, 0, 0);
                acc[0][1] = __builtin_amdgcn_mfma_f32_32x32x16_bf16(a0l, b1h, acc[0][1], 0, 0, 0);
                acc[1][0] = __builtin_amdgcn_mfma_f32_32x32x16_bf16(a1l, b0h, acc[1][0], 0, 0, 0);
                acc[1][1] = __builtin_amdgcn_mfma_f32_32x32x16_bf16(a1l, b1h, acc[1][1], 0, 0, 0);
            }
        }
        // epilogue: running (best, idx, second) per row-slot
        #pragma unroll
        for (int tm = 0; tm < 2; ++tm)
            #pragma unroll
            for (int r = 0; r < 16; ++r) {
                float s0 = fmaf(-2.0f, acc[tm][0][r], wnA);
                bool c0 = s0 < bv[tm][r];
                sv[tm][r] = fminf(sv[tm][r], c0 ? bv[tm][r] : s0);
                bv[tm][r] = c0 ? s0 : bv[tm][r];
                bi[tm][r] = c0 ? cA : bi[tm][r];
                float s1 = fmaf(-2.0f, acc[tm][1][r], wnB);
                bool c1 = s1 < bv[tm][r];
                sv[tm][r] = fminf(sv[tm][r], c1 ? bv[tm][r] : s1);
                bv[tm][r] = c1 ? s1 : bv[tm][r];
                bi[tm][r] = c1 ? cB : bi[tm][r];
            }
    }
    // merge across the 32 lanes sharing each row set, then lock-free global top-2
    #pragma unroll
    for (int tm = 0; tm < 2; ++tm)
        #pragma unroll
        for (int r = 0; r < 16; ++r) {
            unsigned long long key =
                ((unsigned long long)f2key(bv[tm][r]) << 32) | bi[tm][r];
            unsigned sk = f2key(sv[tm][r]);
            #pragma unroll
            for (int m = 1; m < 32; m <<= 1) {
                unsigned long long ko = __shfl_xor(key, m, 64);
                unsigned sko = __shfl_xor(sk, m, 64);
                unsigned long long loser = key < ko ? ko : key;
                sk = min(min(sk, sko), (unsigned)(loser >> 32));
                key = key < ko ? key : ko;
            }
            if (l31 == 0) {
                const int grow = r0 + wr * 64 + tm * 32 + (r & 3) + 8 * (r >> 2) + 4 * h;
                unsigned long long old = atomicMin(&keys[grow], key);
                if (old != ~0ull) {
                    unsigned long long loser = old < key ? key : old;
                    atomicMin(&keys2[grow], (unsigned)(loser >> 32));
                }
                atomicMin(&keys2[grow], sk);
            }
        }
}

// ---------------- flag near-ties ----------------
extern "C" __global__ void flag_kernel(unsigned long long* __restrict__ keys,
                                       const unsigned* __restrict__ keys2,
                                       int* __restrict__ list, int* __restrict__ count) {
    const int row = blockIdx.x * 256 + threadIdx.x;
    unsigned long long k = keys[row];
    float b = key2f((unsigned)(k >> 32));
    float s = key2f(keys2[row]);
    if (s - b < EPS_GAP) {
        int p = atomicAdd(count, 1);
        list[p] = row;
        keys[row] = ~0ull;   // rerank rebuilds from scratch
    }
}

// ---------------- exact f32 rerank of flagged rows ----------------
// grid 2048 x 256: block covers 4 codes (one per 64-lane group).
// 4-row ILP: four independent load->fma->shuffle chains per iteration
// (r3: 1-row serial chain was latency-bound, VALUBusy 11%).
extern "C" __global__ void rerank_kernel(const float* __restrict__ lat,
                                         const float* __restrict__ cbk,
                                         const float* __restrict__ wnorm,
                                         const int* __restrict__ list,
                                         const int* __restrict__ count,
                                         unsigned long long* __restrict__ keys) {
    const int slot = threadIdx.x >> 6, lane = threadIdx.x & 63;
    const int code = blockIdx.x * 4 + slot;
    const float4 wv = *(const float4*)&cbk[(size_t)code * C_DIM + lane * 4];
    const float wn = wnorm[code];
    const int n = *count;
    int i = 0;
    for (; i + 4 <= n; i += 4) {
        const int r0 = list[i], r1 = list[i + 1], r2 = list[i + 2], r3 = list[i + 3];
        float4 x0 = *(const float4*)&lat[(size_t)r0 * C_DIM + lane * 4];
        float4 x1 = *(const float4*)&lat[(size_t)r1 * C_DIM + lane * 4];
        float4 x2 = *(const float4*)&lat[(size_t)r2 * C_DIM + lane * 4];
        float4 x3 = *(const float4*)&lat[(size_t)r3 * C_DIM + lane * 4];
        float d0 = x0.x * wv.x; d0 = fmaf(x0.y, wv.y, d0); d0 = fmaf(x0.z, wv.z, d0); d0 = fmaf(x0.w, wv.w, d0);
        float d1 = x1.x * wv.x; d1 = fmaf(x1.y, wv.y, d1); d1 = fmaf(x1.z, wv.z, d1); d1 = fmaf(x1.w, wv.w, d1);
        float d2 = x2.x * wv.x; d2 = fmaf(x2.y, wv.y, d2); d2 = fmaf(x2.z, wv.z, d2); d2 = fmaf(x2.w, wv.w, d2);
        float d3 = x3.x * wv.x; d3 = fmaf(x3.y, wv.y, d3); d3 = fmaf(x3.z, wv.z, d3); d3 = fmaf(x3.w, wv.w, d3);
        #pragma unroll
        for (int m = 1; m < 64; m <<= 1) {
            d0 += __shfl_xor(d0, m, 64);
            d1 += __shfl_xor(d1, m, 64);
            d2 += __shfl_xor(d2, m, 64);
            d3 += __shfl_xor(d3, m, 64);
        }
        if (lane == 0) {
            atomicMin(&keys[r0], ((unsigned long long)f2key(fmaf(-2.0f, d0, wn)) << 32) | (unsigned)code);
            atomicMin(&keys[r1], ((unsigned long long)f2key(fmaf(-2.0f, d1, wn)) << 32) | (unsigned)code);
            atomicMin(&keys[r2], ((unsigned long long)f2key(fmaf(-2.0f, d2, wn)) << 32) | (unsigned)code);
            atomicMin(&keys[r3], ((unsigned long long)f2key(fmaf(-2.0f, d3, wn)) << 32) | (unsigned)code);
        }
    }
    for (; i < n; ++i) {
        const int row = list[i];
        float4 xv = *(const float4*)&lat[(size_t)row * C_DIM + lane * 4];
        float d = xv.x * wv.x;
        d = fmaf(xv.y, wv.y, d);
        d = fmaf(xv.z, wv.z, d);
        d = fmaf(xv.w, wv.w, d);
        #pragma unroll
        for (int m = 1; m < 64; m <<= 1) d += __shfl_xor(d, m, 64);
        if (lane == 0) {
            float s = fmaf(-2.0f, d, wn);
            atomicMin(&keys[row], ((unsigned long long)f2key(s) << 32) | (unsigned)code);
        }
    }
}

// ---------------- finalize ----------------
extern "C" __global__ void finalize_kernel(const float* __restrict__ lat,
                                           const float* __restrict__ cbk,
                                           const float* __restrict__ noise,
                                           const unsigned long long* __restrict__ keys,
                                           float* __restrict__ out) {
    const int row = blockIdx.x;
    const int c = threadIdx.x;
    const unsigned long long p = keys[row];
    const int id = (int)(unsigned)(p & 0xFFFFFFFFull);
    const int off = (int)rintf(noise[row] * 0.5f);
    int idn = id + off;
    idn = idn < 0 ? 0 : (idn > K_CODES - 1 ? K_CODES - 1 : idn);
    const float x  = lat[(size_t)row * C_DIM + c];
    const float qd = cbk[(size_t)id  * C_DIM + c];
    const float qn = cbk[(size_t)idn * C_DIM + c];
    out[(size_t)row * C_DIM + c] = x + (qn - x);
    const float d1 = x - qd;
    const float d2 = qn - x;
    float t = (0.25f * d1 * d1 + d2 * d2) * (1.0f / 4194304.0f);
    #pragma unroll
    for (int m = 32; m; m >>= 1) t += __shfl_xor(t, m, 64);
    __shared__ float red[4];
    if ((c & 63) == 0) red[c >> 6] = t;
    __syncthreads();
    if (c == 0) {
        atomicAdd(out + (size_t)N_ROWS * C_DIM, red[0] + red[1] + red[2] + red[3]);
        out[(size_t)N_ROWS * C_DIM + 1 + row] = (float)idn;
    }
}

extern "C" void kernel_launch(void* const* d_in, const int* in_sizes, int n_in,
                              void* d_out, int out_size, void* d_ws, size_t ws_size,
                              hipStream_t stream) {
    const float* lat   = (const float*)d_in[0];
    const float* cbk   = (const float*)d_in[1];
    const float* noise = (const float*)d_in[2];
    float* out = (float*)d_out;

    char* ws = (char*)d_ws;
    unsigned short* xh = (unsigned short*)(ws);                    //  8 MB
    unsigned short* xl = (unsigned short*)(ws + 8388608);          //  8 MB
    unsigned short* wh = (unsigned short*)(ws + 16777216);         //  4 MB
    unsigned short* wl = (unsigned short*)(ws + 20971520);         //  4 MB
    float* wnorm       = (float*)(ws + 25165824);                  // 32 KB
    unsigned long long* keys = (unsigned long long*)(ws + 25198592); // 128 KB
    unsigned* keys2    = (unsigned*)(ws + 25329664);               // 64 KB
    int* list          = (int*)(ws + 25395200);                    // 64 KB
    int* count         = (int*)(ws + 25460736);

    hipMemsetAsync(keys,  0xFF, (size_t)N_ROWS * 8, stream);
    hipMemsetAsync(keys2, 0xFF, (size_t)N_ROWS * 4, stream);
    hipMemsetAsync(count, 0, sizeof(int), stream);
    hipMemsetAsync(out + (size_t)N_ROWS * C_DIM, 0, sizeof(float), stream);

    prep_kernel<<<2048, 256, 0, stream>>>(lat, xh, xl);
    prep_kernel<<<1024, 256, 0, stream>>>(cbk, wh, wl);
    wnorm_kernel<<<K_CODES / 4, 256, 0, stream>>>(cbk, wnorm);
    pass1_kernel<<<1024, 256, 0, stream>>>(xh, xl, wh, wl, wnorm, keys, keys2);
    flag_kernel<<<N_ROWS / 256, 256, 0, stream>>>(keys, keys2, list, count);
    rerank_kernel<<<K_CODES / 4, 256, 0, stream>>>(lat, cbk, wnorm, list, count, keys);
    finalize_kernel<<<N_ROWS, 256, 0, stream>>>(lat, cbk, noise, keys, out);
}

// Round 5
// 487.801 us; speedup vs baseline: 2.2107x; 1.4616x over previous
//
#include <hip/hip_runtime.h>
#include <hip/hip_bf16.h>

// PSN: quantize latents (16384 x 256) f32 against codebook (8192 x 256) f32.
// Outputs (flat f32): st[16384*256], loss[1], inds_noisy[16384] (as float).
//
// Pipeline: prep(split f32 -> bf16 hi/lo) -> wnorm -> MFMA approx argmin with
// top-2 tracking (swizzled LDS, 2-phase reg-staged pipeline) -> flag near-ties
// -> exact f32 rerank of flagged rows -> finalize + loss reduce.

namespace {
constexpr int N_ROWS  = 16384;
constexpr int K_CODES = 8192;
constexpr int C_DIM   = 256;
constexpr float EPS_GAP = 0.008f;   // ~8x the worst-case bf16-split score error
}

typedef __attribute__((ext_vector_type(8)))  short bf16x8;
typedef __attribute__((ext_vector_type(16))) float f32x16;

__device__ __forceinline__ unsigned f2key(float f) {
    unsigned u = __float_as_uint(f);
    return (u & 0x80000000u) ? ~u : (u | 0x80000000u);
}
__device__ __forceinline__ float key2f(unsigned k) {
    unsigned u = (k & 0x80000000u) ? (k ^ 0x80000000u) : ~k;
    return __uint_as_float(u);
}
__device__ __forceinline__ unsigned short f2bf(float x) {
    unsigned u = __float_as_uint(x);
    unsigned r = u + 0x7fffu + ((u >> 16) & 1u);   // RNE
    return (unsigned short)(r >> 16);
}

// ---------------- prep: f32 -> (bf16 hi, bf16 lo) ----------------
extern "C" __global__ void prep_kernel(const float* __restrict__ src,
                                       unsigned short* __restrict__ hi,
                                       unsigned short* __restrict__ lo) {
    const int i = (blockIdx.x * 256 + threadIdx.x) * 8;
    float4 a = *(const float4*)&src[i];
    float4 b = *(const float4*)&src[i + 4];
    float v[8] = {a.x, a.y, a.z, a.w, b.x, b.y, b.z, b.w};
    unsigned short h[8], l[8];
    #pragma unroll
    for (int j = 0; j < 8; ++j) {
        h[j] = f2bf(v[j]);
        float hf = __uint_as_float((unsigned)h[j] << 16);
        l[j] = f2bf(v[j] - hf);
    }
    ushort4 h0 = {h[0], h[1], h[2], h[3]}, h1 = {h[4], h[5], h[6], h[7]};
    ushort4 l0 = {l[0], l[1], l[2], l[3]}, l1 = {l[4], l[5], l[6], l[7]};
    *(ushort4*)&hi[i] = h0;  *(ushort4*)&hi[i + 4] = h1;
    *(ushort4*)&lo[i] = l0;  *(ushort4*)&lo[i + 4] = l1;
}

// ---------------- wnorm ----------------
extern "C" __global__ void wnorm_kernel(const float* __restrict__ cbk,
                                        float* __restrict__ wnorm) {
    const int k = blockIdx.x * 4 + (threadIdx.x >> 6);
    const int lane = threadIdx.x & 63;
    float4 v = reinterpret_cast<const float4*>(cbk + (size_t)k * C_DIM)[lane];
    float s = v.x * v.x + v.y * v.y + v.z * v.z + v.w * v.w;
    #pragma unroll
    for (int m = 32; m; m >>= 1) s += __shfl_xor(s, m, 64);
    if (lane == 0) wnorm[k] = s;
}

// ---------------- pass1: MFMA approx argmin, top-2 per row ----------------
// grid 1024: rb = bid&127 (128-row block), cs = bid>>7 (1024-code split).
// block 256 = 4 waves (2 row x 2 col), wave tile 64x64, mfma 32x32x16.
// LDS: linear [row][32 bf16] tiles (64B rows), quarter swizzle
// q' = q ^ ((row>>1)&3) -> conflict-free b128 reads AND writes (r4 had 4-way,
// 16.8M conflict cycles). 2-phase pipeline: write LDS(t); barrier; issue
// global loads(t+1); MFMA(t) -> global latency hides under MFMA.
extern "C" __global__ void __launch_bounds__(256, 2)
pass1_kernel(const unsigned short* __restrict__ xh_g,
             const unsigned short* __restrict__ xl_g,
             const unsigned short* __restrict__ wh_g,
             const unsigned short* __restrict__ wl_g,
             const float* __restrict__ wnorm,
             unsigned long long* __restrict__ keys,
             unsigned* __restrict__ keys2) {
    __shared__ __align__(16) unsigned short XH[128 * 32], XL[128 * 32];
    __shared__ __align__(16) unsigned short WH[128 * 32], WL[128 * 32];
    const int tid = threadIdx.x;
    const int lane = tid & 63;
    const int wid = tid >> 6;
    const int wr = wid >> 1, wc = wid & 1;
    const int h = lane >> 5;
    const int l31 = lane & 31;
    const int rb = blockIdx.x & 127, cs = blockIdx.x >> 7;
    const int r0 = rb * 128, cbase = cs * 1024;

    // staging map: j in {0,1}: row = (tid>>2) + 64*j, quarter q = tid&3
    const int srow = tid >> 2, sq = tid & 3;
    const int soff0 = srow * 32 + ((sq ^ ((srow >> 1) & 3)) << 3);
    const int srow1 = srow + 64;
    const int soff1 = srow1 * 32 + ((sq ^ ((srow1 >> 1) & 3)) << 3);

    // fragment rows (per lane) + their swizzle phase (same for +32 rows)
    const int rA0 = wr * 64 + l31, rA1 = rA0 + 32;
    const int rB0 = wc * 64 + l31, rB1 = rB0 + 32;
    const int fA = (rA0 >> 1) & 3;
    const int fB = (rB0 >> 1) & 3;

    float bv[2][16];  unsigned bi[2][16];  float sv[2][16];
    #pragma unroll
    for (int tm = 0; tm < 2; ++tm)
        #pragma unroll
        for (int r = 0; r < 16; ++r) { bv[tm][r] = 3.4e38f; sv[tm][r] = 3.4e38f; bi[tm][r] = 0; }

    f32x16 acc[2][2];
    #pragma unroll
    for (int tm = 0; tm < 2; ++tm)
        #pragma unroll
        for (int tn = 0; tn < 2; ++tn)
            #pragma unroll
            for (int e = 0; e < 16; ++e) acc[tm][tn][e] = 0.0f;

    // named staging regs (avoid runtime-indexed arrays -> scratch)
    uint4 sxh0, sxh1, sxl0, sxl1, swh0, swh1, swl0, swl1;

    auto loadt = [&](int t) {
        const int kc32 = (t & 7) * 32;
        const int cb = cbase + (t >> 3) * 128;
        const size_t xo0 = (size_t)(r0 + srow) * 256 + kc32 + sq * 8;
        const size_t xo1 = xo0 + 64 * 256;
        const size_t wo0 = (size_t)(cb + srow) * 256 + kc32 + sq * 8;
        const size_t wo1 = wo0 + 64 * 256;
        sxh0 = *(const uint4*)(xh_g + xo0);  sxh1 = *(const uint4*)(xh_g + xo1);
        sxl0 = *(const uint4*)(xl_g + xo0);  sxl1 = *(const uint4*)(xl_g + xo1);
        swh0 = *(const uint4*)(wh_g + wo0);  swh1 = *(const uint4*)(wh_g + wo1);
        swl0 = *(const uint4*)(wl_g + wo0);  swl1 = *(const uint4*)(wl_g + wo1);
    };

    loadt(0);
    for (int t = 0; t < 64; ++t) {
        __syncthreads();             // prior tile's reads done
        *(uint4*)&XH[soff0] = sxh0;  *(uint4*)&XH[soff1] = sxh1;
        *(uint4*)&XL[soff0] = sxl0;  *(uint4*)&XL[soff1] = sxl1;
        *(uint4*)&WH[soff0] = swh0;  *(uint4*)&WH[soff1] = swh1;
        *(uint4*)&WL[soff0] = swl0;  *(uint4*)&WL[soff1] = swl1;
        __syncthreads();             // tile visible
        if (t < 63) loadt(t + 1);    // overlap next-tile loads with MFMA

        #pragma unroll
        for (int kk = 0; kk < 2; ++kk) {
            const int q = kk * 2 + h;
            const int aA0 = rA0 * 32 + ((q ^ fA) << 3);
            const int aA1 = rA1 * 32 + ((q ^ fA) << 3);
            const int aB0 = rB0 * 32 + ((q ^ fB) << 3);
            const int aB1 = rB1 * 32 + ((q ^ fB) << 3);
            bf16x8 a0h = *(const bf16x8*)&XH[aA0];
            bf16x8 a1h = *(const bf16x8*)&XH[aA1];
            bf16x8 a0l = *(const bf16x8*)&XL[aA0];
            bf16x8 a1l = *(const bf16x8*)&XL[aA1];
            bf16x8 b0h = *(const bf16x8*)&WH[aB0];
            bf16x8 b1h = *(const bf16x8*)&WH[aB1];
            bf16x8 b0l = *(const bf16x8*)&WL[aB0];
            bf16x8 b1l = *(const bf16x8*)&WL[aB1];
            acc[0][0] = __builtin_amdgcn_mfma_f32_32x32x16_bf16(a0h, b0h, acc[0][0], 0, 0, 0);
            acc[0][1] = __builtin_amdgcn_mfma_f32_32x32x16_bf16(a0h, b1h, acc[0][1], 0, 0, 0);
            acc[1][0] = __builtin_amdgcn_mfma_f32_32x32x16_bf16(a1h, b0h, acc[1][0], 0, 0, 0);
            acc[1][1] = __builtin_amdgcn_mfma_f32_32x32x16_bf16(a1h, b1h, acc[1][1], 0, 0, 0);
            acc[0][0] = __builtin_amdgcn_mfma_f32_32x32x16_bf16(a0h, b0l, acc[0][0], 0, 0, 0);
            acc[0][1] = __builtin_amdgcn_mfma_f32_32x32x16_bf16(a0h, b1l, acc[0][1], 0, 0, 0);
            acc[1][0] = __builtin_amdgcn_mfma_f32_32x32x16_bf16(a1h, b0l, acc[1][0], 0, 0, 0);
            acc[1][1] = __builtin_amdgcn_mfma_f32_32x32x16_bf16(a1h, b1l, acc[1][1], 0, 0, 0);
            acc[0][0] = __builtin_amdgcn_mfma_f32_32x32x16_bf16(a0l, b0h, acc[0][0], 0, 0, 0);
            acc[0][1] = __builtin_amdgcn_mfma_f32_32x32x16_bf16(a0l, b1h, acc[0][1], 0, 0, 0);
            acc[1][0] = __builtin_amdgcn_mfma_f32_32x32x16_bf16(a1l, b0h, acc[1][0], 0, 0, 0);
            acc[1][1] = __builtin_amdgcn_mfma_f32_32x32x16_bf16(a1l, b1h, acc[1][1], 0, 0, 0);
        }

        if ((t & 7) == 7) {
            // epilogue for code tile ct = t>>3 (codes cb .. cb+127)
            const int cb = cbase + (t >> 3) * 128;
            const float wnA = wnorm[cb + wc * 64 + l31];
            const float wnB = wnorm[cb + wc * 64 + 32 + l31];
            const unsigned cA = cb + wc * 64 + l31;
            const unsigned cB = cA + 32;
            #pragma unroll
            for (int tm = 0; tm < 2; ++tm)
                #pragma unroll
                for (int r = 0; r < 16; ++r) {
                    float s0 = fmaf(-2.0f, acc[tm][0][r], wnA);
                    bool c0 = s0 < bv[tm][r];
                    sv[tm][r] = fminf(sv[tm][r], c0 ? bv[tm][r] : s0);
                    bv[tm][r] = c0 ? s0 : bv[tm][r];
                    bi[tm][r] = c0 ? cA : bi[tm][r];
                    float s1 = fmaf(-2.0f, acc[tm][1][r], wnB);
                    bool c1 = s1 < bv[tm][r];
                    sv[tm][r] = fminf(sv[tm][r], c1 ? bv[tm][r] : s1);
                    bv[tm][r] = c1 ? s1 : bv[tm][r];
                    bi[tm][r] = c1 ? cB : bi[tm][r];
                }
            #pragma unroll
            for (int tm = 0; tm < 2; ++tm)
                #pragma unroll
                for (int tn = 0; tn < 2; ++tn)
                    #pragma unroll
                    for (int e = 0; e < 16; ++e) acc[tm][tn][e] = 0.0f;
        }
    }

    // merge across the 32 lanes sharing each row set, then lock-free global top-2
    #pragma unroll
    for (int tm = 0; tm < 2; ++tm)
        #pragma unroll
        for (int r = 0; r < 16; ++r) {
            unsigned long long key =
                ((unsigned long long)f2key(bv[tm][r]) << 32) | bi[tm][r];
            unsigned sk = f2key(sv[tm][r]);
            #pragma unroll
            for (int m = 1; m < 32; m <<= 1) {
                unsigned long long ko = __shfl_xor(key, m, 64);
                unsigned sko = __shfl_xor(sk, m, 64);
                unsigned long long loser = key < ko ? ko : key;
                sk = min(min(sk, sko), (unsigned)(loser >> 32));
                key = key < ko ? key : ko;
            }
            if (l31 == 0) {
                const int grow = r0 + wr * 64 + tm * 32 + (r & 3) + 8 * (r >> 2) + 4 * h;
                unsigned long long old = atomicMin(&keys[grow], key);
                if (old != ~0ull) {
                    unsigned long long loser = old < key ? key : old;
                    atomicMin(&keys2[grow], (unsigned)(loser >> 32));
                }
                atomicMin(&keys2[grow], sk);
            }
        }
}

// ---------------- flag near-ties ----------------
extern "C" __global__ void flag_kernel(unsigned long long* __restrict__ keys,
                                       const unsigned* __restrict__ keys2,
                                       int* __restrict__ list, int* __restrict__ count) {
    const int row = blockIdx.x * 256 + threadIdx.x;
    unsigned long long k = keys[row];
    float b = key2f((unsigned)(k >> 32));
    float s = key2f(keys2[row]);
    if (s - b < EPS_GAP) {
        int p = atomicAdd(count, 1);
        list[p] = row;
        keys[row] = ~0ull;   // rerank rebuilds from scratch
    }
}

// ---------------- exact f32 rerank of flagged rows (8-row ILP) ----------------
extern "C" __global__ void rerank_kernel(const float* __restrict__ lat,
                                         const float* __restrict__ cbk,
                                         const float* __restrict__ wnorm,
                                         const int* __restrict__ list,
                                         const int* __restrict__ count,
                                         unsigned long long* __restrict__ keys) {
    const int slot = threadIdx.x >> 6, lane = threadIdx.x & 63;
    const int code = blockIdx.x * 4 + slot;
    const float4 wv = *(const float4*)&cbk[(size_t)code * C_DIM + lane * 4];
    const float wn = wnorm[code];
    const int n = *count;
    int i = 0;
    for (; i + 8 <= n; i += 8) {
        int rr[8]; float dd[8];
        #pragma unroll
        for (int j = 0; j < 8; ++j) rr[j] = list[i + j];
        #pragma unroll
        for (int j = 0; j < 8; ++j) {
            float4 xv = *(const float4*)&lat[(size_t)rr[j] * C_DIM + lane * 4];
            float d = xv.x * wv.x;
            d = fmaf(xv.y, wv.y, d);
            d = fmaf(xv.z, wv.z, d);
            dd[j] = fmaf(xv.w, wv.w, d);
        }
        #pragma unroll
        for (int m = 1; m < 64; m <<= 1) {
            #pragma unroll
            for (int j = 0; j < 8; ++j) dd[j] += __shfl_xor(dd[j], m, 64);
        }
        if (lane == 0) {
            #pragma unroll
            for (int j = 0; j < 8; ++j)
                atomicMin(&keys[rr[j]],
                          ((unsigned long long)f2key(fmaf(-2.0f, dd[j], wn)) << 32) | (unsigned)code);
        }
    }
    for (; i < n; ++i) {
        const int row = list[i];
        float4 xv = *(const float4*)&lat[(size_t)row * C_DIM + lane * 4];
        float d = xv.x * wv.x;
        d = fmaf(xv.y, wv.y, d);
        d = fmaf(xv.z, wv.z, d);
        d = fmaf(xv.w, wv.w, d);
        #pragma unroll
        for (int m = 1; m < 64; m <<= 1) d += __shfl_xor(d, m, 64);
        if (lane == 0) {
            float s = fmaf(-2.0f, d, wn);
            atomicMin(&keys[row], ((unsigned long long)f2key(s) << 32) | (unsigned)code);
        }
    }
}

// ---------------- finalize (loss -> 1024 partial slots, no hot atomic) ------
extern "C" __global__ void finalize_kernel(const float* __restrict__ lat,
                                           const float* __restrict__ cbk,
                                           const float* __restrict__ noise,
                                           const unsigned long long* __restrict__ keys,
                                           float* __restrict__ out,
                                           float* __restrict__ lpart) {
    const int row = blockIdx.x;
    const int c = threadIdx.x;
    const unsigned long long p = keys[row];
    const int id = (int)(unsigned)(p & 0xFFFFFFFFull);
    const int off = (int)rintf(noise[row] * 0.5f);
    int idn = id + off;
    idn = idn < 0 ? 0 : (idn > K_CODES - 1 ? K_CODES - 1 : idn);
    const float x  = lat[(size_t)row * C_DIM + c];
    const float qd = cbk[(size_t)id  * C_DIM + c];
    const float qn = cbk[(size_t)idn * C_DIM + c];
    out[(size_t)row * C_DIM + c] = x + (qn - x);
    const float d1 = x - qd;
    const float d2 = qn - x;
    float t = (0.25f * d1 * d1 + d2 * d2) * (1.0f / 4194304.0f);
    #pragma unroll
    for (int m = 32; m; m >>= 1) t += __shfl_xor(t, m, 64);
    __shared__ float red[4];
    if ((c & 63) == 0) red[c >> 6] = t;
    __syncthreads();
    if (c == 0) {
        atomicAdd(&lpart[row & 1023], red[0] + red[1] + red[2] + red[3]);
        out[(size_t)N_ROWS * C_DIM + 1 + row] = (float)idn;
    }
}

extern "C" __global__ void loss_reduce_kernel(const float* __restrict__ lpart,
                                              float* __restrict__ out) {
    const int t = threadIdx.x;
    float s = lpart[t] + lpart[t + 256] + lpart[t + 512] + lpart[t + 768];
    #pragma unroll
    for (int m = 32; m; m >>= 1) s += __shfl_xor(s, m, 64);
    __shared__ float red[4];
    if ((t & 63) == 0) red[t >> 6] = s;
    __syncthreads();
    if (t == 0) out[(size_t)N_ROWS * C_DIM] = red[0] + red[1] + red[2] + red[3];
}

extern "C" void kernel_launch(void* const* d_in, const int* in_sizes, int n_in,
                              void* d_out, int out_size, void* d_ws, size_t ws_size,
                              hipStream_t stream) {
    const float* lat   = (const float*)d_in[0];
    const float* cbk   = (const float*)d_in[1];
    const float* noise = (const float*)d_in[2];
    float* out = (float*)d_out;

    char* ws = (char*)d_ws;
    unsigned short* xh = (unsigned short*)(ws);                      //  8 MB
    unsigned short* xl = (unsigned short*)(ws + 8388608);            //  8 MB
    unsigned short* wh = (unsigned short*)(ws + 16777216);           //  4 MB
    unsigned short* wl = (unsigned short*)(ws + 20971520);           //  4 MB
    float* wnorm       = (float*)(ws + 25165824);                    // 32 KB
    unsigned long long* keys = (unsigned long long*)(ws + 25198592); // 128 KB
    unsigned* keys2    = (unsigned*)(ws + 25329664);                 // 64 KB
    int* list          = (int*)(ws + 25395200);                      // 64 KB
    int* count         = (int*)(ws + 25460736);                      // 4 KB pad
    float* lpart       = (float*)(ws + 25464832);                    // 4 KB

    hipMemsetAsync(keys,  0xFF, (size_t)N_ROWS * 8, stream);
    hipMemsetAsync(keys2, 0xFF, (size_t)N_ROWS * 4, stream);
    hipMemsetAsync(count, 0, sizeof(int), stream);
    hipMemsetAsync(lpart, 0, 1024 * sizeof(float), stream);

    prep_kernel<<<2048, 256, 0, stream>>>(lat, xh, xl);
    prep_kernel<<<1024, 256, 0, stream>>>(cbk, wh, wl);
    wnorm_kernel<<<K_CODES / 4, 256, 0, stream>>>(cbk, wnorm);
    pass1_kernel<<<1024, 256, 0, stream>>>(xh, xl, wh, wl, wnorm, keys, keys2);
    flag_kernel<<<N_ROWS / 256, 256, 0, stream>>>(keys, keys2, list, count);
    rerank_kernel<<<K_CODES / 4, 256, 0, stream>>>(lat, cbk, wnorm, list, count, keys);
    finalize_kernel<<<N_ROWS, 256, 0, stream>>>(lat, cbk, noise, keys, out, lpart);
    loss_reduce_kernel<<<1, 256, 0, stream>>>(lpart, out);
}

// Round 6
// 485.120 us; speedup vs baseline: 2.2229x; 1.0055x over previous
//
#include <hip/hip_runtime.h>
#include <hip/hip_bf16.h>

// PSN: quantize latents (16384 x 256) f32 against codebook (8192 x 256) f32.
// Outputs (flat f32): st[16384*256], loss[1], inds_noisy[16384] (as float).
//
// Pipeline: prep(split f32 -> bf16 hi/lo) -> wnorm -> MFMA approx argmin with
// top-2 tracking (double-buffered LDS, 1 barrier/tile) -> flag near-ties ->
// exact f32 rerank of flagged rows -> finalize + loss reduce.

namespace {
constexpr int N_ROWS  = 16384;
constexpr int K_CODES = 8192;
constexpr int C_DIM   = 256;
// score-error tail ~1e-3 (2^-16-scale split residuals); 4x margin.
constexpr float EPS_GAP = 0.004f;
}

typedef __attribute__((ext_vector_type(8)))  short bf16x8;
typedef __attribute__((ext_vector_type(16))) float f32x16;

__device__ __forceinline__ unsigned f2key(float f) {
    unsigned u = __float_as_uint(f);
    return (u & 0x80000000u) ? ~u : (u | 0x80000000u);
}
__device__ __forceinline__ float key2f(unsigned k) {
    unsigned u = (k & 0x80000000u) ? (k ^ 0x80000000u) : ~k;
    return __uint_as_float(u);
}
__device__ __forceinline__ unsigned short f2bf(float x) {
    unsigned u = __float_as_uint(x);
    unsigned r = u + 0x7fffu + ((u >> 16) & 1u);   // RNE
    return (unsigned short)(r >> 16);
}

// ---------------- prep: f32 -> (bf16 hi, bf16 lo) ----------------
extern "C" __global__ void prep_kernel(const float* __restrict__ src,
                                       unsigned short* __restrict__ hi,
                                       unsigned short* __restrict__ lo) {
    const int i = (blockIdx.x * 256 + threadIdx.x) * 8;
    float4 a = *(const float4*)&src[i];
    float4 b = *(const float4*)&src[i + 4];
    float v[8] = {a.x, a.y, a.z, a.w, b.x, b.y, b.z, b.w};
    unsigned short h[8], l[8];
    #pragma unroll
    for (int j = 0; j < 8; ++j) {
        h[j] = f2bf(v[j]);
        float hf = __uint_as_float((unsigned)h[j] << 16);
        l[j] = f2bf(v[j] - hf);
    }
    ushort4 h0 = {h[0], h[1], h[2], h[3]}, h1 = {h[4], h[5], h[6], h[7]};
    ushort4 l0 = {l[0], l[1], l[2], l[3]}, l1 = {l[4], l[5], l[6], l[7]};
    *(ushort4*)&hi[i] = h0;  *(ushort4*)&hi[i + 4] = h1;
    *(ushort4*)&lo[i] = l0;  *(ushort4*)&lo[i + 4] = l1;
}

// ---------------- wnorm ----------------
extern "C" __global__ void wnorm_kernel(const float* __restrict__ cbk,
                                        float* __restrict__ wnorm) {
    const int k = blockIdx.x * 4 + (threadIdx.x >> 6);
    const int lane = threadIdx.x & 63;
    float4 v = reinterpret_cast<const float4*>(cbk + (size_t)k * C_DIM)[lane];
    float s = v.x * v.x + v.y * v.y + v.z * v.z + v.w * v.w;
    #pragma unroll
    for (int m = 32; m; m >>= 1) s += __shfl_xor(s, m, 64);
    if (lane == 0) wnorm[k] = s;
}

// ---------------- pass1: MFMA approx argmin, top-2 per row ----------------
// grid 1024: rb = bid&127 (128-row block), cs = bid>>7 (1024-code split).
// block 256 = 4 waves (2 row x 2 col), wave tile 64x64, mfma 32x32x16.
// Double-buffered LDS, ONE barrier per tile (r5: 2-barrier loop was ~75%
// stall; vmcnt wait now sits after the MFMA cluster so load latency hides
// under the full compute span).
extern "C" __global__ void __launch_bounds__(256, 2)
pass1_kernel(const unsigned short* __restrict__ xh_g,
             const unsigned short* __restrict__ xl_g,
             const unsigned short* __restrict__ wh_g,
             const unsigned short* __restrict__ wl_g,
             const float* __restrict__ wnorm,
             unsigned long long* __restrict__ keys,
             unsigned* __restrict__ keys2) {
    __shared__ __align__(16) unsigned short XH[2][128 * 32], XL[2][128 * 32];
    __shared__ __align__(16) unsigned short WH[2][128 * 32], WL[2][128 * 32];
    const int tid = threadIdx.x;
    const int lane = tid & 63;
    const int wid = tid >> 6;
    const int wr = wid >> 1, wc = wid & 1;
    const int h = lane >> 5;
    const int l31 = lane & 31;
    const int rb = blockIdx.x & 127, cs = blockIdx.x >> 7;
    const int r0 = rb * 128, cbase = cs * 1024;

    // staging map: rows (tid>>2) and +64, quarter q = tid&3 (swizzled)
    const int srow = tid >> 2, sq = tid & 3;
    const int soff0 = srow * 32 + ((sq ^ ((srow >> 1) & 3)) << 3);
    const int srow1 = srow + 64;
    const int soff1 = srow1 * 32 + ((sq ^ ((srow1 >> 1) & 3)) << 3);

    // fragment rows (per lane) + swizzle phase
    const int rA0 = wr * 64 + l31, rA1 = rA0 + 32;
    const int rB0 = wc * 64 + l31, rB1 = rB0 + 32;
    const int fA = (rA0 >> 1) & 3;
    const int fB = (rB0 >> 1) & 3;

    float bv[2][16];  unsigned bi[2][16];  float sv[2][16];
    #pragma unroll
    for (int tm = 0; tm < 2; ++tm)
        #pragma unroll
        for (int r = 0; r < 16; ++r) { bv[tm][r] = 3.4e38f; sv[tm][r] = 3.4e38f; bi[tm][r] = 0; }

    f32x16 acc[2][2];
    #pragma unroll
    for (int tm = 0; tm < 2; ++tm)
        #pragma unroll
        for (int tn = 0; tn < 2; ++tn)
            #pragma unroll
            for (int e = 0; e < 16; ++e) acc[tm][tn][e] = 0.0f;

    uint4 sxh0, sxh1, sxl0, sxl1, swh0, swh1, swl0, swl1;   // staging regs

    auto loadt = [&](int t) {
        const int kc32 = (t & 7) * 32;
        const int cb = cbase + (t >> 3) * 128;
        const size_t xo0 = (size_t)(r0 + srow) * 256 + kc32 + sq * 8;
        const size_t xo1 = xo0 + 64 * 256;
        const size_t wo0 = (size_t)(cb + srow) * 256 + kc32 + sq * 8;
        const size_t wo1 = wo0 + 64 * 256;
        sxh0 = *(const uint4*)(xh_g + xo0);  sxh1 = *(const uint4*)(xh_g + xo1);
        sxl0 = *(const uint4*)(xl_g + xo0);  sxl1 = *(const uint4*)(xl_g + xo1);
        swh0 = *(const uint4*)(wh_g + wo0);  swh1 = *(const uint4*)(wh_g + wo1);
        swl0 = *(const uint4*)(wl_g + wo0);  swl1 = *(const uint4*)(wl_g + wo1);
    };
    auto storet = [&](int p) {
        *(uint4*)&XH[p][soff0] = sxh0;  *(uint4*)&XH[p][soff1] = sxh1;
        *(uint4*)&XL[p][soff0] = sxl0;  *(uint4*)&XL[p][soff1] = sxl1;
        *(uint4*)&WH[p][soff0] = swh0;  *(uint4*)&WH[p][soff1] = swh1;
        *(uint4*)&WL[p][soff0] = swl0;  *(uint4*)&WL[p][soff1] = swl1;
    };

    loadt(0);
    storet(0);
    int p = 0;
    for (int t = 0; t < 64; ++t) {
        __syncthreads();                 // buf p fully written, other buf free
        if (t < 63) loadt(t + 1);        // issue early (hides under MFMA)

        #pragma unroll
        for (int kk = 0; kk < 2; ++kk) {
            const int q = kk * 2 + h;
            const int aA0 = rA0 * 32 + ((q ^ fA) << 3);
            const int aA1 = rA1 * 32 + ((q ^ fA) << 3);
            const int aB0 = rB0 * 32 + ((q ^ fB) << 3);
            const int aB1 = rB1 * 32 + ((q ^ fB) << 3);
            bf16x8 a0h = *(const bf16x8*)&XH[p][aA0];
            bf16x8 a1h = *(const bf16x8*)&XH[p][aA1];
            bf16x8 a0l = *(const bf16x8*)&XL[p][aA0];
            bf16x8 a1l = *(const bf16x8*)&XL[p][aA1];
            bf16x8 b0h = *(const bf16x8*)&WH[p][aB0];
            bf16x8 b1h = *(const bf16x8*)&WH[p][aB1];
            bf16x8 b0l = *(const bf16x8*)&WL[p][aB0];
            bf16x8 b1l = *(const bf16x8*)&WL[p][aB1];
            acc[0][0] = __builtin_amdgcn_mfma_f32_32x32x16_bf16(a0h, b0h, acc[0][0], 0, 0, 0);
            acc[0][1] = __builtin_amdgcn_mfma_f32_32x32x16_bf16(a0h, b1h, acc[0][1], 0, 0, 0);
            acc[1][0] = __builtin_amdgcn_mfma_f32_32x32x16_bf16(a1h, b0h, acc[1][0], 0, 0, 0);
            acc[1][1] = __builtin_amdgcn_mfma_f32_32x32x16_bf16(a1h, b1h, acc[1][1], 0, 0, 0);
            acc[0][0] = __builtin_amdgcn_mfma_f32_32x32x16_bf16(a0h, b0l, acc[0][0], 0, 0, 0);
            acc[0][1] = __builtin_amdgcn_mfma_f32_32x32x16_bf16(a0h, b1l, acc[0][1], 0, 0, 0);
            acc[1][0] = __builtin_amdgcn_mfma_f32_32x32x16_bf16(a1h, b0l, acc[1][0], 0, 0, 0);
            acc[1][1] = __builtin_amdgcn_mfma_f32_32x32x16_bf16(a1h, b1l, acc[1][1], 0, 0, 0);
            acc[0][0] = __builtin_amdgcn_mfma_f32_32x32x16_bf16(a0l, b0h, acc[0][0], 0, 0, 0);
            acc[0][1] = __builtin_amdgcn_mfma_f32_32x32x16_bf16(a0l, b1h, acc[0][1], 0, 0, 0);
            acc[1][0] = __builtin_amdgcn_mfma_f32_32x32x16_bf16(a1l, b0h, acc[1][0], 0, 0, 0);
            acc[1][1] = __builtin_amdgcn_mfma_f32_32x32x16_bf16(a1l, b1h, acc[1][1], 0, 0, 0);
        }

        if ((t & 7) == 7) {
            const int cb = cbase + (t >> 3) * 128;
            const float wnA = wnorm[cb + wc * 64 + l31];
            const float wnB = wnorm[cb + wc * 64 + 32 + l31];
            const unsigned cA = cb + wc * 64 + l31;
            const unsigned cB = cA + 32;
            #pragma unroll
            for (int tm = 0; tm < 2; ++tm)
                #pragma unroll
                for (int r = 0; r < 16; ++r) {
                    float s0 = fmaf(-2.0f, acc[tm][0][r], wnA);
                    bool c0 = s0 < bv[tm][r];
                    sv[tm][r] = fminf(sv[tm][r], c0 ? bv[tm][r] : s0);
                    bv[tm][r] = c0 ? s0 : bv[tm][r];
                    bi[tm][r] = c0 ? cA : bi[tm][r];
                    float s1 = fmaf(-2.0f, acc[tm][1][r], wnB);
                    bool c1 = s1 < bv[tm][r];
                    sv[tm][r] = fminf(sv[tm][r], c1 ? bv[tm][r] : s1);
                    bv[tm][r] = c1 ? s1 : bv[tm][r];
                    bi[tm][r] = c1 ? cB : bi[tm][r];
                }
            #pragma unroll
            for (int tm = 0; tm < 2; ++tm)
                #pragma unroll
                for (int tn = 0; tn < 2; ++tn)
                    #pragma unroll
                    for (int e = 0; e < 16; ++e) acc[tm][tn][e] = 0.0f;
        }

        if (t < 63) storet(p ^ 1);       // waits vmcnt internally; after MFMA
        p ^= 1;
    }

    // merge across the 32 lanes sharing each row set, then lock-free global top-2
    #pragma unroll
    for (int tm = 0; tm < 2; ++tm)
        #pragma unroll
        for (int r = 0; r < 16; ++r) {
            unsigned long long key =
                ((unsigned long long)f2key(bv[tm][r]) << 32) | bi[tm][r];
            unsigned sk = f2key(sv[tm][r]);
            #pragma unroll
            for (int m = 1; m < 32; m <<= 1) {
                unsigned long long ko = __shfl_xor(key, m, 64);
                unsigned sko = __shfl_xor(sk, m, 64);
                unsigned long long loser = key < ko ? ko : key;
                sk = min(min(sk, sko), (unsigned)(loser >> 32));
                key = key < ko ? key : ko;
            }
            if (l31 == 0) {
                const int grow = r0 + wr * 64 + tm * 32 + (r & 3) + 8 * (r >> 2) + 4 * h;
                unsigned long long old = atomicMin(&keys[grow], key);
                if (old != ~0ull) {
                    unsigned long long loser = old < key ? key : old;
                    atomicMin(&keys2[grow], (unsigned)(loser >> 32));
                }
                atomicMin(&keys2[grow], sk);
            }
        }
}

// ---------------- flag near-ties ----------------
extern "C" __global__ void flag_kernel(unsigned long long* __restrict__ keys,
                                       const unsigned* __restrict__ keys2,
                                       int* __restrict__ list, int* __restrict__ count) {
    const int row = blockIdx.x * 256 + threadIdx.x;
    unsigned long long k = keys[row];
    float b = key2f((unsigned)(k >> 32));
    float s = key2f(keys2[row]);
    if (s - b < EPS_GAP) {
        int p = atomicAdd(count, 1);
        list[p] = row;
        keys[row] = ~0ull;   // rerank rebuilds from scratch
    }
}

// ---------------- exact f32 rerank of flagged rows (8-row ILP) ----------------
extern "C" __global__ void rerank_kernel(const float* __restrict__ lat,
                                         const float* __restrict__ cbk,
                                         const float* __restrict__ wnorm,
                                         const int* __restrict__ list,
                                         const int* __restrict__ count,
                                         unsigned long long* __restrict__ keys) {
    const int slot = threadIdx.x >> 6, lane = threadIdx.x & 63;
    const int code = blockIdx.x * 4 + slot;
    const float4 wv = *(const float4*)&cbk[(size_t)code * C_DIM + lane * 4];
    const float wn = wnorm[code];
    const int n = *count;
    int i = 0;
    for (; i + 8 <= n; i += 8) {
        int rr[8]; float dd[8];
        #pragma unroll
        for (int j = 0; j < 8; ++j) rr[j] = list[i + j];
        #pragma unroll
        for (int j = 0; j < 8; ++j) {
            float4 xv = *(const float4*)&lat[(size_t)rr[j] * C_DIM + lane * 4];
            float d = xv.x * wv.x;
            d = fmaf(xv.y, wv.y, d);
            d = fmaf(xv.z, wv.z, d);
            dd[j] = fmaf(xv.w, wv.w, d);
        }
        #pragma unroll
        for (int m = 1; m < 64; m <<= 1) {
            #pragma unroll
            for (int j = 0; j < 8; ++j) dd[j] += __shfl_xor(dd[j], m, 64);
        }
        if (lane == 0) {
            #pragma unroll
            for (int j = 0; j < 8; ++j)
                atomicMin(&keys[rr[j]],
                          ((unsigned long long)f2key(fmaf(-2.0f, dd[j], wn)) << 32) | (unsigned)code);
        }
    }
    for (; i < n; ++i) {
        const int row = list[i];
        float4 xv = *(const float4*)&lat[(size_t)row * C_DIM + lane * 4];
        float d = xv.x * wv.x;
        d = fmaf(xv.y, wv.y, d);
        d = fmaf(xv.z, wv.z, d);
        d = fmaf(xv.w, wv.w, d);
        #pragma unroll
        for (int m = 1; m < 64; m <<= 1) d += __shfl_xor(d, m, 64);
        if (lane == 0) {
            float s = fmaf(-2.0f, d, wn);
            atomicMin(&keys[row], ((unsigned long long)f2key(s) << 32) | (unsigned)code);
        }
    }
}

// ---------------- finalize (loss -> 1024 partial slots) ----------------
extern "C" __global__ void finalize_kernel(const float* __restrict__ lat,
                                           const float* __restrict__ cbk,
                                           const float* __restrict__ noise,
                                           const unsigned long long* __restrict__ keys,
                                           float* __restrict__ out,
                                           float* __restrict__ lpart) {
    const int row = blockIdx.x;
    const int c = threadIdx.x;
    const unsigned long long p = keys[row];
    const int id = (int)(unsigned)(p & 0xFFFFFFFFull);
    const int off = (int)rintf(noise[row] * 0.5f);
    int idn = id + off;
    idn = idn < 0 ? 0 : (idn > K_CODES - 1 ? K_CODES - 1 : idn);
    const float x  = lat[(size_t)row * C_DIM + c];
    const float qd = cbk[(size_t)id  * C_DIM + c];
    const float qn = cbk[(size_t)idn * C_DIM + c];
    out[(size_t)row * C_DIM + c] = x + (qn - x);
    const float d1 = x - qd;
    const float d2 = qn - x;
    float t = (0.25f * d1 * d1 + d2 * d2) * (1.0f / 4194304.0f);
    #pragma unroll
    for (int m = 32; m; m >>= 1) t += __shfl_xor(t, m, 64);
    __shared__ float red[4];
    if ((c & 63) == 0) red[c >> 6] = t;
    __syncthreads();
    if (c == 0) {
        atomicAdd(&lpart[row & 1023], red[0] + red[1] + red[2] + red[3]);
        out[(size_t)N_ROWS * C_DIM + 1 + row] = (float)idn;
    }
}

extern "C" __global__ void loss_reduce_kernel(const float* __restrict__ lpart,
                                              float* __restrict__ out) {
    const int t = threadIdx.x;
    float s = lpart[t] + lpart[t + 256] + lpart[t + 512] + lpart[t + 768];
    #pragma unroll
    for (int m = 32; m; m >>= 1) s += __shfl_xor(s, m, 64);
    __shared__ float red[4];
    if ((t & 63) == 0) red[t >> 6] = s;
    __syncthreads();
    if (t == 0) out[(size_t)N_ROWS * C_DIM] = red[0] + red[1] + red[2] + red[3];
}

extern "C" void kernel_launch(void* const* d_in, const int* in_sizes, int n_in,
                              void* d_out, int out_size, void* d_ws, size_t ws_size,
                              hipStream_t stream) {
    const float* lat   = (const float*)d_in[0];
    const float* cbk   = (const float*)d_in[1];
    const float* noise = (const float*)d_in[2];
    float* out = (float*)d_out;

    char* ws = (char*)d_ws;
    unsigned short* xh = (unsigned short*)(ws);                      //  8 MB
    unsigned short* xl = (unsigned short*)(ws + 8388608);            //  8 MB
    unsigned short* wh = (unsigned short*)(ws + 16777216);           //  4 MB
    unsigned short* wl = (unsigned short*)(ws + 20971520);           //  4 MB
    float* wnorm       = (float*)(ws + 25165824);                    // 32 KB
    unsigned long long* keys = (unsigned long long*)(ws + 25198592); // 128 KB
    unsigned* keys2    = (unsigned*)(ws + 25329664);                 // 64 KB
    int* list          = (int*)(ws + 25395200);                      // 64 KB
    int* count         = (int*)(ws + 25460736);                      // 4 KB pad
    float* lpart       = (float*)(ws + 25464832);                    // 4 KB

    hipMemsetAsync(keys,  0xFF, (size_t)N_ROWS * 8, stream);
    hipMemsetAsync(keys2, 0xFF, (size_t)N_ROWS * 4, stream);
    hipMemsetAsync(count, 0, sizeof(int), stream);
    hipMemsetAsync(lpart, 0, 1024 * sizeof(float), stream);

    prep_kernel<<<2048, 256, 0, stream>>>(lat, xh, xl);
    prep_kernel<<<1024, 256, 0, stream>>>(cbk, wh, wl);
    wnorm_kernel<<<K_CODES / 4, 256, 0, stream>>>(cbk, wnorm);
    pass1_kernel<<<1024, 256, 0, stream>>>(xh, xl, wh, wl, wnorm, keys, keys2);
    flag_kernel<<<N_ROWS / 256, 256, 0, stream>>>(keys, keys2, list, count);
    rerank_kernel<<<K_CODES / 4, 256, 0, stream>>>(lat, cbk, wnorm, list, count, keys);
    finalize_kernel<<<N_ROWS, 256, 0, stream>>>(lat, cbk, noise, keys, out, lpart);
    loss_reduce_kernel<<<1, 256, 0, stream>>>(lpart, out);
}

// Round 7
// 459.894 us; speedup vs baseline: 2.3448x; 1.0549x over previous
//
#include <hip/hip_runtime.h>
#include <hip/hip_bf16.h>

// PSN: quantize latents (16384 x 256) f32 against codebook (8192 x 256) f32.
// Outputs (flat f32): st[16384*256], loss[1], inds_noisy[16384] (as float).
//
// Pipeline: prep(split f32 -> bf16 hi/lo; cbk path fuses wnorm) -> MFMA approx
// argmin with top-2 tracking (global_load_lds staging, pre-swizzled source,
// double-buffered LDS, 1 barrier/tile) -> flag near-ties -> exact f32 rerank
// of flagged rows -> finalize + loss reduce.

namespace {
constexpr int N_ROWS  = 16384;
constexpr int K_CODES = 8192;
constexpr int C_DIM   = 256;
constexpr float EPS_GAP = 0.004f;   // ~4x the bf16-split score-error tail
}

typedef __attribute__((ext_vector_type(8)))  short bf16x8;
typedef __attribute__((ext_vector_type(16))) float f32x16;

typedef __attribute__((address_space(1))) const unsigned int gas_u32;
typedef __attribute__((address_space(3))) unsigned int las_u32;

__device__ __forceinline__ void gld16(const unsigned short* g, unsigned short* l) {
    // 16B per lane, LDS dest = wave-uniform base + lane*16 (HW rule, m104)
    __builtin_amdgcn_global_load_lds((gas_u32*)g, (las_u32*)l, 16, 0, 0);
}

__device__ __forceinline__ unsigned f2key(float f) {
    unsigned u = __float_as_uint(f);
    return (u & 0x80000000u) ? ~u : (u | 0x80000000u);
}
__device__ __forceinline__ float key2f(unsigned k) {
    unsigned u = (k & 0x80000000u) ? (k ^ 0x80000000u) : ~k;
    return __uint_as_float(u);
}
__device__ __forceinline__ unsigned short f2bf(float x) {
    unsigned u = __float_as_uint(x);
    unsigned r = u + 0x7fffu + ((u >> 16) & 1u);   // RNE
    return (unsigned short)(r >> 16);
}

// ---------------- prep latents: f32 -> (bf16 hi, bf16 lo) ----------------
extern "C" __global__ void prep_kernel(const float* __restrict__ src,
                                       unsigned short* __restrict__ hi,
                                       unsigned short* __restrict__ lo) {
    const int i = (blockIdx.x * 256 + threadIdx.x) * 8;
    float4 a = *(const float4*)&src[i];
    float4 b = *(const float4*)&src[i + 4];
    float v[8] = {a.x, a.y, a.z, a.w, b.x, b.y, b.z, b.w};
    unsigned short h[8], l[8];
    #pragma unroll
    for (int j = 0; j < 8; ++j) {
        h[j] = f2bf(v[j]);
        float hf = __uint_as_float((unsigned)h[j] << 16);
        l[j] = f2bf(v[j] - hf);
    }
    ushort4 h0 = {h[0], h[1], h[2], h[3]}, h1 = {h[4], h[5], h[6], h[7]};
    ushort4 l0 = {l[0], l[1], l[2], l[3]}, l1 = {l[4], l[5], l[6], l[7]};
    *(ushort4*)&hi[i] = h0;  *(ushort4*)&hi[i + 4] = h1;
    *(ushort4*)&lo[i] = l0;  *(ushort4*)&lo[i + 4] = l1;
}

// ---------------- prep codebook: split + fused wnorm ----------------
extern "C" __global__ void prepw_kernel(const float* __restrict__ src,
                                        unsigned short* __restrict__ hi,
                                        unsigned short* __restrict__ lo,
                                        float* __restrict__ wnorm) {
    const int i = (blockIdx.x * 256 + threadIdx.x) * 8;   // 8 elems, one row per 32 threads
    float4 a = *(const float4*)&src[i];
    float4 b = *(const float4*)&src[i + 4];
    float v[8] = {a.x, a.y, a.z, a.w, b.x, b.y, b.z, b.w};
    unsigned short h[8], l[8];
    float s = 0.0f;
    #pragma unroll
    for (int j = 0; j < 8; ++j) {
        h[j] = f2bf(v[j]);
        float hf = __uint_as_float((unsigned)h[j] << 16);
        l[j] = f2bf(v[j] - hf);
        s = fmaf(v[j], v[j], s);
    }
    ushort4 h0 = {h[0], h[1], h[2], h[3]}, h1 = {h[4], h[5], h[6], h[7]};
    ushort4 l0 = {l[0], l[1], l[2], l[3]}, l1 = {l[4], l[5], l[6], l[7]};
    *(ushort4*)&hi[i] = h0;  *(ushort4*)&hi[i + 4] = h1;
    *(ushort4*)&lo[i] = l0;  *(ushort4*)&lo[i + 4] = l1;
    #pragma unroll
    for (int m = 1; m < 32; m <<= 1) s += __shfl_xor(s, m, 64);  // 32-lane group
    if ((threadIdx.x & 31) == 0) wnorm[i >> 8] = s;
}

// ---------------- pass1: MFMA approx argmin, top-2 per row ----------------
// grid 1024: rb = bid&127 (128-row block), cs = bid>>7 (1024-code split).
// block 256 = 4 waves (2 row x 2 col), wave tile 64x64, mfma 32x32x16.
// Staging via global_load_lds width=16 (no ds_writes, no staging VGPRs);
// swizzle q' = q ^ ((row>>1)&3) realized by pre-swizzling the GLOBAL source
// per lane (LDS dest stays linear per HW rule). For 16-row chunks the phase
// is lane-constant: (l>>3)&3; fetch quarter = (l&3) ^ ((l>>3)&3).
extern "C" __global__ void __launch_bounds__(256, 2)
pass1_kernel(const unsigned short* __restrict__ xh_g,
             const unsigned short* __restrict__ xl_g,
             const unsigned short* __restrict__ wh_g,
             const unsigned short* __restrict__ wl_g,
             const float* __restrict__ wnorm,
             unsigned long long* __restrict__ keys,
             unsigned* __restrict__ keys2) {
    __shared__ __align__(16) unsigned short LDS[2][4][128 * 32];  // [buf][XH,XL,WH,WL]
    const int tid = threadIdx.x;
    const int lane = tid & 63;
    const int wid = tid >> 6;
    const int wr = wid >> 1, wc = wid & 1;
    const int h = lane >> 5;
    const int l31 = lane & 31;
    const int rb = blockIdx.x & 127, cs = blockIdx.x >> 7;
    const int r0 = rb * 128, cbase = cs * 1024;

    // per-lane staging constants (pre-swizzled global quarter)
    const int dr = lane >> 2;
    const int gq = (lane & 3) ^ ((lane >> 3) & 3);
    const int laneoff = dr * 256 + gq * 8;

    // fragment rows (per lane) + swizzle phase
    const int rA0 = wr * 64 + l31, rA1 = rA0 + 32;
    const int rB0 = wc * 64 + l31, rB1 = rB0 + 32;
    const int fA = (rA0 >> 1) & 3;
    const int fB = (rB0 >> 1) & 3;

    float bv[2][16];  unsigned bi[2][16];  float sv[2][16];
    #pragma unroll
    for (int tm = 0; tm < 2; ++tm)
        #pragma unroll
        for (int r = 0; r < 16; ++r) { bv[tm][r] = 3.4e38f; sv[tm][r] = 3.4e38f; bi[tm][r] = 0; }

    f32x16 acc[2][2];
    #pragma unroll
    for (int tm = 0; tm < 2; ++tm)
        #pragma unroll
        for (int tn = 0; tn < 2; ++tn)
            #pragma unroll
            for (int e = 0; e < 16; ++e) acc[tm][tn][e] = 0.0f;

    auto stage = [&](int t, int b) {
        const int kc32 = (t & 7) * 32;
        const int cb = cbase + (t >> 3) * 128;
        #pragma unroll
        for (int c = 0; c < 2; ++c) {
            const int R = wid * 32 + c * 16;            // wave-uniform chunk base
            const size_t xg = (size_t)(r0 + R) * 256 + kc32 + laneoff;
            const size_t wg = (size_t)(cb + R) * 256 + kc32 + laneoff;
            gld16(xh_g + xg, &LDS[b][0][R * 32]);
            gld16(xl_g + xg, &LDS[b][1][R * 32]);
            gld16(wh_g + wg, &LDS[b][2][R * 32]);
            gld16(wl_g + wg, &LDS[b][3][R * 32]);
        }
    };

    stage(0, 0);
    __syncthreads();          // vmcnt drain: buf0 ready
    int p = 0;
    for (int t = 0; t < 64; ++t) {
        if (t < 63) stage(t + 1, p ^ 1);   // in flight under the MFMA cluster

        #pragma unroll
        for (int kk = 0; kk < 2; ++kk) {
            const int q = kk * 2 + h;
            const int aA0 = rA0 * 32 + ((q ^ fA) << 3);
            const int aA1 = rA1 * 32 + ((q ^ fA) << 3);
            const int aB0 = rB0 * 32 + ((q ^ fB) << 3);
            const int aB1 = rB1 * 32 + ((q ^ fB) << 3);
            bf16x8 a0h = *(const bf16x8*)&LDS[p][0][aA0];
            bf16x8 a1h = *(const bf16x8*)&LDS[p][0][aA1];
            bf16x8 a0l = *(const bf16x8*)&LDS[p][1][aA0];
            bf16x8 a1l = *(const bf16x8*)&LDS[p][1][aA1];
            bf16x8 b0h = *(const bf16x8*)&LDS[p][2][aB0];
            bf16x8 b1h = *(const bf16x8*)&LDS[p][2][aB1];
            bf16x8 b0l = *(const bf16x8*)&LDS[p][3][aB0];
            bf16x8 b1l = *(const bf16x8*)&LDS[p][3][aB1];
            acc[0][0] = __builtin_amdgcn_mfma_f32_32x32x16_bf16(a0h, b0h, acc[0][0], 0, 0, 0);
            acc[0][1] = __builtin_amdgcn_mfma_f32_32x32x16_bf16(a0h, b1h, acc[0][1], 0, 0, 0);
            acc[1][0] = __builtin_amdgcn_mfma_f32_32x32x16_bf16(a1h, b0h, acc[1][0], 0, 0, 0);
            acc[1][1] = __builtin_amdgcn_mfma_f32_32x32x16_bf16(a1h, b1h, acc[1][1], 0, 0, 0);
            acc[0][0] = __builtin_amdgcn_mfma_f32_32x32x16_bf16(a0h, b0l, acc[0][0], 0, 0, 0);
            acc[0][1] = __builtin_amdgcn_mfma_f32_32x32x16_bf16(a0h, b1l, acc[0][1], 0, 0, 0);
            acc[1][0] = __builtin_amdgcn_mfma_f32_32x32x16_bf16(a1h, b0l, acc[1][0], 0, 0, 0);
            acc[1][1] = __builtin_amdgcn_mfma_f32_32x32x16_bf16(a1h, b1l, acc[1][1], 0, 0, 0);
            acc[0][0] = __builtin_amdgcn_mfma_f32_32x32x16_bf16(a0l, b0h, acc[0][0], 0, 0, 0);
            acc[0][1] = __builtin_amdgcn_mfma_f32_32x32x16_bf16(a0l, b1h, acc[0][1], 0, 0, 0);
            acc[1][0] = __builtin_amdgcn_mfma_f32_32x32x16_bf16(a1l, b0h, acc[1][0], 0, 0, 0);
            acc[1][1] = __builtin_amdgcn_mfma_f32_32x32x16_bf16(a1l, b1h, acc[1][1], 0, 0, 0);
        }

        if ((t & 7) == 7) {
            const int cb = cbase + (t >> 3) * 128;
            const float wnA = wnorm[cb + wc * 64 + l31];
            const float wnB = wnorm[cb + wc * 64 + 32 + l31];
            const unsigned cA = cb + wc * 64 + l31;
            const unsigned cB = cA + 32;
            #pragma unroll
            for (int tm = 0; tm < 2; ++tm)
                #pragma unroll
                for (int r = 0; r < 16; ++r) {
                    float s0 = fmaf(-2.0f, acc[tm][0][r], wnA);
                    bool c0 = s0 < bv[tm][r];
                    sv[tm][r] = fminf(sv[tm][r], c0 ? bv[tm][r] : s0);
                    bv[tm][r] = c0 ? s0 : bv[tm][r];
                    bi[tm][r] = c0 ? cA : bi[tm][r];
                    float s1 = fmaf(-2.0f, acc[tm][1][r], wnB);
                    bool c1 = s1 < bv[tm][r];
                    sv[tm][r] = fminf(sv[tm][r], c1 ? bv[tm][r] : s1);
                    bv[tm][r] = c1 ? s1 : bv[tm][r];
                    bi[tm][r] = c1 ? cB : bi[tm][r];
                }
            #pragma unroll
            for (int tm = 0; tm < 2; ++tm)
                #pragma unroll
                for (int tn = 0; tn < 2; ++tn)
                    #pragma unroll
                    for (int e = 0; e < 16; ++e) acc[tm][tn][e] = 0.0f;
        }

        __syncthreads();      // drains vmcnt (stage done) + lgkm (reads done)
        p ^= 1;
    }

    // merge across the 32 lanes sharing each row set, then lock-free global top-2
    #pragma unroll
    for (int tm = 0; tm < 2; ++tm)
        #pragma unroll
        for (int r = 0; r < 16; ++r) {
            unsigned long long key =
                ((unsigned long long)f2key(bv[tm][r]) << 32) | bi[tm][r];
            unsigned sk = f2key(sv[tm][r]);
            #pragma unroll
            for (int m = 1; m < 32; m <<= 1) {
                unsigned long long ko = __shfl_xor(key, m, 64);
                unsigned sko = __shfl_xor(sk, m, 64);
                unsigned long long loser = key < ko ? ko : key;
                sk = min(min(sk, sko), (unsigned)(loser >> 32));
                key = key < ko ? key : ko;
            }
            if (l31 == 0) {
                const int grow = r0 + wr * 64 + tm * 32 + (r & 3) + 8 * (r >> 2) + 4 * h;
                unsigned long long old = atomicMin(&keys[grow], key);
                if (old != ~0ull) {
                    unsigned long long loser = old < key ? key : old;
                    atomicMin(&keys2[grow], (unsigned)(loser >> 32));
                }
                atomicMin(&keys2[grow], sk);
            }
        }
}

// ---------------- flag near-ties ----------------
extern "C" __global__ void flag_kernel(unsigned long long* __restrict__ keys,
                                       const unsigned* __restrict__ keys2,
                                       int* __restrict__ list, int* __restrict__ count) {
    const int row = blockIdx.x * 256 + threadIdx.x;
    unsigned long long k = keys[row];
    float b = key2f((unsigned)(k >> 32));
    float s = key2f(keys2[row]);
    if (s - b < EPS_GAP) {
        int p = atomicAdd(count, 1);
        list[p] = row;
        keys[row] = ~0ull;   // rerank rebuilds from scratch
    }
}

// ---------------- exact f32 rerank of flagged rows (8-row ILP) ----------------
extern "C" __global__ void rerank_kernel(const float* __restrict__ lat,
                                         const float* __restrict__ cbk,
                                         const float* __restrict__ wnorm,
                                         const int* __restrict__ list,
                                         const int* __restrict__ count,
                                         unsigned long long* __restrict__ keys) {
    const int slot = threadIdx.x >> 6, lane = threadIdx.x & 63;
    const int code = blockIdx.x * 4 + slot;
    const float4 wv = *(const float4*)&cbk[(size_t)code * C_DIM + lane * 4];
    const float wn = wnorm[code];
    const int n = *count;
    int i = 0;
    for (; i + 8 <= n; i += 8) {
        int rr[8]; float dd[8];
        #pragma unroll
        for (int j = 0; j < 8; ++j) rr[j] = list[i + j];
        #pragma unroll
        for (int j = 0; j < 8; ++j) {
            float4 xv = *(const float4*)&lat[(size_t)rr[j] * C_DIM + lane * 4];
            float d = xv.x * wv.x;
            d = fmaf(xv.y, wv.y, d);
            d = fmaf(xv.z, wv.z, d);
            dd[j] = fmaf(xv.w, wv.w, d);
        }
        #pragma unroll
        for (int m = 1; m < 64; m <<= 1) {
            #pragma unroll
            for (int j = 0; j < 8; ++j) dd[j] += __shfl_xor(dd[j], m, 64);
        }
        if (lane == 0) {
            #pragma unroll
            for (int j = 0; j < 8; ++j)
                atomicMin(&keys[rr[j]],
                          ((unsigned long long)f2key(fmaf(-2.0f, dd[j], wn)) << 32) | (unsigned)code);
        }
    }
    for (; i < n; ++i) {
        const int row = list[i];
        float4 xv = *(const float4*)&lat[(size_t)row * C_DIM + lane * 4];
        float d = xv.x * wv.x;
        d = fmaf(xv.y, wv.y, d);
        d = fmaf(xv.z, wv.z, d);
        d = fmaf(xv.w, wv.w, d);
        #pragma unroll
        for (int m = 1; m < 64; m <<= 1) d += __shfl_xor(d, m, 64);
        if (lane == 0) {
            float s = fmaf(-2.0f, d, wn);
            atomicMin(&keys[row], ((unsigned long long)f2key(s) << 32) | (unsigned)code);
        }
    }
}

// ---------------- finalize: 8 rows/block (2048 blocks) ----------------
extern "C" __global__ void finalize_kernel(const float* __restrict__ lat,
                                           const float* __restrict__ cbk,
                                           const float* __restrict__ noise,
                                           const unsigned long long* __restrict__ keys,
                                           float* __restrict__ out,
                                           float* __restrict__ lpart) {
    const int g = threadIdx.x >> 5;          // row group 0..7
    const int l = threadIdx.x & 31;
    const int row = blockIdx.x * 8 + g;
    const unsigned long long p = keys[row];
    const int id = (int)(unsigned)(p & 0xFFFFFFFFull);
    const int off = (int)rintf(noise[row] * 0.5f);
    int idn = id + off;
    idn = idn < 0 ? 0 : (idn > K_CODES - 1 ? K_CODES - 1 : idn);
    const float4* latp = (const float4*)&lat[(size_t)row * C_DIM];
    const float4* qdp  = (const float4*)&cbk[(size_t)id  * C_DIM];
    const float4* qnp  = (const float4*)&cbk[(size_t)idn * C_DIM];
    float4* stp = (float4*)&out[(size_t)row * C_DIM];
    float t = 0.0f;
    #pragma unroll
    for (int j = 0; j < 2; ++j) {
        const int e = l + j * 32;
        float4 x  = latp[e];
        float4 qd = qdp[e];
        float4 qn = qnp[e];
        float4 st = {x.x + (qn.x - x.x), x.y + (qn.y - x.y),
                     x.z + (qn.z - x.z), x.w + (qn.w - x.w)};
        stp[e] = st;
        float d1, d2;
        d1 = x.x - qd.x; d2 = qn.x - x.x; t += 0.25f * d1 * d1 + d2 * d2;
        d1 = x.y - qd.y; d2 = qn.y - x.y; t += 0.25f * d1 * d1 + d2 * d2;
        d1 = x.z - qd.z; d2 = qn.z - x.z; t += 0.25f * d1 * d1 + d2 * d2;
        d1 = x.w - qd.w; d2 = qn.w - x.w; t += 0.25f * d1 * d1 + d2 * d2;
    }
    t *= (1.0f / 4194304.0f);
    #pragma unroll
    for (int m = 1; m < 32; m <<= 1) t += __shfl_xor(t, m, 64);   // 32-lane group
    __shared__ float red[8];
    if (l == 0) {
        red[g] = t;
        out[(size_t)N_ROWS * C_DIM + 1 + row] = (float)idn;
    }
    __syncthreads();
    if (threadIdx.x == 0) {
        float s = red[0] + red[1] + red[2] + red[3] + red[4] + red[5] + red[6] + red[7];
        atomicAdd(&lpart[blockIdx.x & 1023], s);
    }
}

extern "C" __global__ void loss_reduce_kernel(const float* __restrict__ lpart,
                                              float* __restrict__ out) {
    const int t = threadIdx.x;
    float s = lpart[t] + lpart[t + 256] + lpart[t + 512] + lpart[t + 768];
    #pragma unroll
    for (int m = 32; m; m >>= 1) s += __shfl_xor(s, m, 64);
    __shared__ float red[4];
    if ((t & 63) == 0) red[t >> 6] = s;
    __syncthreads();
    if (t == 0) out[(size_t)N_ROWS * C_DIM] = red[0] + red[1] + red[2] + red[3];
}

extern "C" void kernel_launch(void* const* d_in, const int* in_sizes, int n_in,
                              void* d_out, int out_size, void* d_ws, size_t ws_size,
                              hipStream_t stream) {
    const float* lat   = (const float*)d_in[0];
    const float* cbk   = (const float*)d_in[1];
    const float* noise = (const float*)d_in[2];
    float* out = (float*)d_out;

    char* ws = (char*)d_ws;
    unsigned short* xh = (unsigned short*)(ws);                      //  8 MB
    unsigned short* xl = (unsigned short*)(ws + 8388608);            //  8 MB
    unsigned short* wh = (unsigned short*)(ws + 16777216);           //  4 MB
    unsigned short* wl = (unsigned short*)(ws + 20971520);           //  4 MB
    float* wnorm       = (float*)(ws + 25165824);                    // 32 KB
    unsigned long long* keys = (unsigned long long*)(ws + 25198592); // 128 KB  \ one
    unsigned* keys2    = (unsigned*)(ws + 25329664);                 // 64 KB   / 0xFF memset
    int* list          = (int*)(ws + 25395200);                      // 64 KB
    float* lpart       = (float*)(ws + 25460736);                    // 4 KB    \ one
    int* count         = (int*)(ws + 25464832);                      // 4 B     / 0 memset

    hipMemsetAsync(keys, 0xFF, 192 * 1024, stream);                  // keys + keys2
    hipMemsetAsync(lpart, 0, 4096 + 4, stream);                      // lpart + count

    prep_kernel <<<2048, 256, 0, stream>>>(lat, xh, xl);
    prepw_kernel<<<1024, 256, 0, stream>>>(cbk, wh, wl, wnorm);
    pass1_kernel<<<1024, 256, 0, stream>>>(xh, xl, wh, wl, wnorm, keys, keys2);
    flag_kernel <<<N_ROWS / 256, 256, 0, stream>>>(keys, keys2, list, count);
    rerank_kernel<<<K_CODES / 4, 256, 0, stream>>>(lat, cbk, wnorm, list, count, keys);
    finalize_kernel<<<N_ROWS / 8, 256, 0, stream>>>(lat, cbk, noise, keys, out, lpart);
    loss_reduce_kernel<<<1, 256, 0, stream>>>(lpart, out);
}

// Round 8
// 313.868 us; speedup vs baseline: 3.4358x; 1.4652x over previous
//
#include <hip/hip_runtime.h>
#include <hip/hip_bf16.h>

// PSN: quantize latents (16384 x 256) f32 against codebook (8192 x 256) f32.
// Outputs (flat f32): st[16384*256], loss[1], inds_noisy[16384] (as float).
//
// Pipeline: prep(split f32 -> bf16 hi/lo; cbk path fuses wnorm) -> MFMA approx
// argmin with top-2 tracking (global_load_lds staging, pre-swizzled source,
// double-buffered LDS) -> flag near-ties -> exact f32 rerank of flagged rows
// (code-resident registers, read-before-atomic) -> finalize + loss reduce.

namespace {
constexpr int N_ROWS  = 16384;
constexpr int K_CODES = 8192;
constexpr int C_DIM   = 256;
constexpr float EPS_GAP = 0.004f;   // ~4x the bf16-split score-error tail
}

typedef __attribute__((ext_vector_type(8)))  short bf16x8;
typedef __attribute__((ext_vector_type(16))) float f32x16;

typedef __attribute__((address_space(1))) const unsigned int gas_u32;
typedef __attribute__((address_space(3))) unsigned int las_u32;

__device__ __forceinline__ void gld16(const unsigned short* g, unsigned short* l) {
    __builtin_amdgcn_global_load_lds((gas_u32*)g, (las_u32*)l, 16, 0, 0);
}

__device__ __forceinline__ unsigned f2key(float f) {
    unsigned u = __float_as_uint(f);
    return (u & 0x80000000u) ? ~u : (u | 0x80000000u);
}
__device__ __forceinline__ float key2f(unsigned k) {
    unsigned u = (k & 0x80000000u) ? (k ^ 0x80000000u) : ~k;
    return __uint_as_float(u);
}
__device__ __forceinline__ unsigned short f2bf(float x) {
    unsigned u = __float_as_uint(x);
    unsigned r = u + 0x7fffu + ((u >> 16) & 1u);   // RNE
    return (unsigned short)(r >> 16);
}

// ---------------- prep latents: f32 -> (bf16 hi, bf16 lo) ----------------
extern "C" __global__ void prep_kernel(const float* __restrict__ src,
                                       unsigned short* __restrict__ hi,
                                       unsigned short* __restrict__ lo) {
    const int i = (blockIdx.x * 256 + threadIdx.x) * 8;
    float4 a = *(const float4*)&src[i];
    float4 b = *(const float4*)&src[i + 4];
    float v[8] = {a.x, a.y, a.z, a.w, b.x, b.y, b.z, b.w};
    unsigned short h[8], l[8];
    #pragma unroll
    for (int j = 0; j < 8; ++j) {
        h[j] = f2bf(v[j]);
        float hf = __uint_as_float((unsigned)h[j] << 16);
        l[j] = f2bf(v[j] - hf);
    }
    ushort4 h0 = {h[0], h[1], h[2], h[3]}, h1 = {h[4], h[5], h[6], h[7]};
    ushort4 l0 = {l[0], l[1], l[2], l[3]}, l1 = {l[4], l[5], l[6], l[7]};
    *(ushort4*)&hi[i] = h0;  *(ushort4*)&hi[i + 4] = h1;
    *(ushort4*)&lo[i] = l0;  *(ushort4*)&lo[i + 4] = l1;
}

// ---------------- prep codebook: split + fused wnorm ----------------
extern "C" __global__ void prepw_kernel(const float* __restrict__ src,
                                        unsigned short* __restrict__ hi,
                                        unsigned short* __restrict__ lo,
                                        float* __restrict__ wnorm) {
    const int i = (blockIdx.x * 256 + threadIdx.x) * 8;
    float4 a = *(const float4*)&src[i];
    float4 b = *(const float4*)&src[i + 4];
    float v[8] = {a.x, a.y, a.z, a.w, b.x, b.y, b.z, b.w};
    unsigned short h[8], l[8];
    float s = 0.0f;
    #pragma unroll
    for (int j = 0; j < 8; ++j) {
        h[j] = f2bf(v[j]);
        float hf = __uint_as_float((unsigned)h[j] << 16);
        l[j] = f2bf(v[j] - hf);
        s = fmaf(v[j], v[j], s);
    }
    ushort4 h0 = {h[0], h[1], h[2], h[3]}, h1 = {h[4], h[5], h[6], h[7]};
    ushort4 l0 = {l[0], l[1], l[2], l[3]}, l1 = {l[4], l[5], l[6], l[7]};
    *(ushort4*)&hi[i] = h0;  *(ushort4*)&hi[i + 4] = h1;
    *(ushort4*)&lo[i] = l0;  *(ushort4*)&lo[i + 4] = l1;
    #pragma unroll
    for (int m = 1; m < 32; m <<= 1) s += __shfl_xor(s, m, 64);
    if ((threadIdx.x & 31) == 0) wnorm[i >> 8] = s;
}

// ---------------- pass1: MFMA approx argmin, top-2 per row ----------------
// (unchanged from r7: global_load_lds staging, pre-swizzled source)
extern "C" __global__ void __launch_bounds__(256, 2)
pass1_kernel(const unsigned short* __restrict__ xh_g,
             const unsigned short* __restrict__ xl_g,
             const unsigned short* __restrict__ wh_g,
             const unsigned short* __restrict__ wl_g,
             const float* __restrict__ wnorm,
             unsigned long long* __restrict__ keys,
             unsigned* __restrict__ keys2) {
    __shared__ __align__(16) unsigned short LDS[2][4][128 * 32];
    const int tid = threadIdx.x;
    const int lane = tid & 63;
    const int wid = tid >> 6;
    const int wr = wid >> 1, wc = wid & 1;
    const int h = lane >> 5;
    const int l31 = lane & 31;
    const int rb = blockIdx.x & 127, cs = blockIdx.x >> 7;
    const int r0 = rb * 128, cbase = cs * 1024;

    const int dr = lane >> 2;
    const int gq = (lane & 3) ^ ((lane >> 3) & 3);
    const int laneoff = dr * 256 + gq * 8;

    const int rA0 = wr * 64 + l31, rA1 = rA0 + 32;
    const int rB0 = wc * 64 + l31, rB1 = rB0 + 32;
    const int fA = (rA0 >> 1) & 3;
    const int fB = (rB0 >> 1) & 3;

    float bv[2][16];  unsigned bi[2][16];  float sv[2][16];
    #pragma unroll
    for (int tm = 0; tm < 2; ++tm)
        #pragma unroll
        for (int r = 0; r < 16; ++r) { bv[tm][r] = 3.4e38f; sv[tm][r] = 3.4e38f; bi[tm][r] = 0; }

    f32x16 acc[2][2];
    #pragma unroll
    for (int tm = 0; tm < 2; ++tm)
        #pragma unroll
        for (int tn = 0; tn < 2; ++tn)
            #pragma unroll
            for (int e = 0; e < 16; ++e) acc[tm][tn][e] = 0.0f;

    auto stage = [&](int t, int b) {
        const int kc32 = (t & 7) * 32;
        const int cb = cbase + (t >> 3) * 128;
        #pragma unroll
        for (int c = 0; c < 2; ++c) {
            const int R = wid * 32 + c * 16;
            const size_t xg = (size_t)(r0 + R) * 256 + kc32 + laneoff;
            const size_t wg = (size_t)(cb + R) * 256 + kc32 + laneoff;
            gld16(xh_g + xg, &LDS[b][0][R * 32]);
            gld16(xl_g + xg, &LDS[b][1][R * 32]);
            gld16(wh_g + wg, &LDS[b][2][R * 32]);
            gld16(wl_g + wg, &LDS[b][3][R * 32]);
        }
    };

    stage(0, 0);
    __syncthreads();
    int p = 0;
    for (int t = 0; t < 64; ++t) {
        if (t < 63) stage(t + 1, p ^ 1);

        #pragma unroll
        for (int kk = 0; kk < 2; ++kk) {
            const int q = kk * 2 + h;
            const int aA0 = rA0 * 32 + ((q ^ fA) << 3);
            const int aA1 = rA1 * 32 + ((q ^ fA) << 3);
            const int aB0 = rB0 * 32 + ((q ^ fB) << 3);
            const int aB1 = rB1 * 32 + ((q ^ fB) << 3);
            bf16x8 a0h = *(const bf16x8*)&LDS[p][0][aA0];
            bf16x8 a1h = *(const bf16x8*)&LDS[p][0][aA1];
            bf16x8 a0l = *(const bf16x8*)&LDS[p][1][aA0];
            bf16x8 a1l = *(const bf16x8*)&LDS[p][1][aA1];
            bf16x8 b0h = *(const bf16x8*)&LDS[p][2][aB0];
            bf16x8 b1h = *(const bf16x8*)&LDS[p][2][aB1];
            bf16x8 b0l = *(const bf16x8*)&LDS[p][3][aB0];
            bf16x8 b1l = *(const bf16x8*)&LDS[p][3][aB1];
            acc[0][0] = __builtin_amdgcn_mfma_f32_32x32x16_bf16(a0h, b0h, acc[0][0], 0, 0, 0);
            acc[0][1] = __builtin_amdgcn_mfma_f32_32x32x16_bf16(a0h, b1h, acc[0][1], 0, 0, 0);
            acc[1][0] = __builtin_amdgcn_mfma_f32_32x32x16_bf16(a1h, b0h, acc[1][0], 0, 0, 0);
            acc[1][1] = __builtin_amdgcn_mfma_f32_32x32x16_bf16(a1h, b1h, acc[1][1], 0, 0, 0);
            acc[0][0] = __builtin_amdgcn_mfma_f32_32x32x16_bf16(a0h, b0l, acc[0][0], 0, 0, 0);
            acc[0][1] = __builtin_amdgcn_mfma_f32_32x32x16_bf16(a0h, b1l, acc[0][1], 0, 0, 0);
            acc[1][0] = __builtin_amdgcn_mfma_f32_32x32x16_bf16(a1h, b0l, acc[1][0], 0, 0, 0);
            acc[1][1] = __builtin_amdgcn_mfma_f32_32x32x16_bf16(a1h, b1l, acc[1][1], 0, 0, 0);
            acc[0][0] = __builtin_amdgcn_mfma_f32_32x32x16_bf16(a0l, b0h, acc[0][0], 0, 0, 0);
            acc[0][1] = __builtin_amdgcn_mfma_f32_32x32x16_bf16(a0l, b1h, acc[0][1], 0, 0, 0);
            acc[1][0] = __builtin_amdgcn_mfma_f32_32x32x16_bf16(a1l, b0h, acc[1][0], 0, 0, 0);
            acc[1][1] = __builtin_amdgcn_mfma_f32_32x32x16_bf16(a1l, b1h, acc[1][1], 0, 0, 0);
        }

        if ((t & 7) == 7) {
            const int cb = cbase + (t >> 3) * 128;
            const float wnA = wnorm[cb + wc * 64 + l31];
            const float wnB = wnorm[cb + wc * 64 + 32 + l31];
            const unsigned cA = cb + wc * 64 + l31;
            const unsigned cB = cA + 32;
            #pragma unroll
            for (int tm = 0; tm < 2; ++tm)
                #pragma unroll
                for (int r = 0; r < 16; ++r) {
                    float s0 = fmaf(-2.0f, acc[tm][0][r], wnA);
                    bool c0 = s0 < bv[tm][r];
                    sv[tm][r] = fminf(sv[tm][r], c0 ? bv[tm][r] : s0);
                    bv[tm][r] = c0 ? s0 : bv[tm][r];
                    bi[tm][r] = c0 ? cA : bi[tm][r];
                    float s1 = fmaf(-2.0f, acc[tm][1][r], wnB);
                    bool c1 = s1 < bv[tm][r];
                    sv[tm][r] = fminf(sv[tm][r], c1 ? bv[tm][r] : s1);
                    bv[tm][r] = c1 ? s1 : bv[tm][r];
                    bi[tm][r] = c1 ? cB : bi[tm][r];
                }
            #pragma unroll
            for (int tm = 0; tm < 2; ++tm)
                #pragma unroll
                for (int tn = 0; tn < 2; ++tn)
                    #pragma unroll
                    for (int e = 0; e < 16; ++e) acc[tm][tn][e] = 0.0f;
        }

        __syncthreads();
        p ^= 1;
    }

    #pragma unroll
    for (int tm = 0; tm < 2; ++tm)
        #pragma unroll
        for (int r = 0; r < 16; ++r) {
            unsigned long long key =
                ((unsigned long long)f2key(bv[tm][r]) << 32) | bi[tm][r];
            unsigned sk = f2key(sv[tm][r]);
            #pragma unroll
            for (int m = 1; m < 32; m <<= 1) {
                unsigned long long ko = __shfl_xor(key, m, 64);
                unsigned sko = __shfl_xor(sk, m, 64);
                unsigned long long loser = key < ko ? ko : key;
                sk = min(min(sk, sko), (unsigned)(loser >> 32));
                key = key < ko ? key : ko;
            }
            if (l31 == 0) {
                const int grow = r0 + wr * 64 + tm * 32 + (r & 3) + 8 * (r >> 2) + 4 * h;
                unsigned long long old = atomicMin(&keys[grow], key);
                if (old != ~0ull) {
                    unsigned long long loser = old < key ? key : old;
                    atomicMin(&keys2[grow], (unsigned)(loser >> 32));
                }
                atomicMin(&keys2[grow], sk);
            }
        }
}

// ---------------- flag near-ties ----------------
extern "C" __global__ void flag_kernel(unsigned long long* __restrict__ keys,
                                       const unsigned* __restrict__ keys2,
                                       int* __restrict__ list, int* __restrict__ count) {
    const int row = blockIdx.x * 256 + threadIdx.x;
    unsigned long long k = keys[row];
    float b = key2f((unsigned)(k >> 32));
    float s = key2f(keys2[row]);
    if (s - b < EPS_GAP) {
        int p = atomicAdd(count, 1);
        list[p] = row;
        keys[row] = ~0ull;   // rerank rebuilds from scratch
    }
}

// ---------------- exact f32 rerank (restructured, r7 post-mortem) ----------
// 512 blocks x 256 thr; each wave owns 4 codes RESIDENT in registers
// (c = blk*16 + wave*4 + j). Per flagged row: one x-load, 4 dots, 8
// interleaved shfl trees (2-row unroll), lane0 merges its 4 candidates in
// registers and issues AT MOST ONE atomicMin -- and only if it improves on a
// plain read of keys[row] (keys is monotone decreasing; stale read >= current,
// so skipping when best >= stale is always safe). Kills the n*8192 atomic
// storm of the old structure.
extern "C" __global__ void __launch_bounds__(256)
rerank_kernel(const float* __restrict__ lat,
              const float* __restrict__ cbk,
              const float* __restrict__ wnorm,
              const int* __restrict__ list,
              const int* __restrict__ count,
              unsigned long long* __restrict__ keys) {
    const int w = threadIdx.x >> 6, lane = threadIdx.x & 63;
    const int c0 = blockIdx.x * 16 + w * 4;
    float4 wv0 = *(const float4*)&cbk[(size_t)(c0 + 0) * C_DIM + lane * 4];
    float4 wv1 = *(const float4*)&cbk[(size_t)(c0 + 1) * C_DIM + lane * 4];
    float4 wv2 = *(const float4*)&cbk[(size_t)(c0 + 2) * C_DIM + lane * 4];
    float4 wv3 = *(const float4*)&cbk[(size_t)(c0 + 3) * C_DIM + lane * 4];
    const float wn0 = wnorm[c0 + 0], wn1 = wnorm[c0 + 1];
    const float wn2 = wnorm[c0 + 2], wn3 = wnorm[c0 + 3];
    const int n = *count;

    auto dot4 = [&](const float4& x, const float4& v) {
        float d = x.x * v.x;
        d = fmaf(x.y, v.y, d);
        d = fmaf(x.z, v.z, d);
        return fmaf(x.w, v.w, d);
    };
    auto best4 = [&](float a0, float a1, float a2, float a3) {
        unsigned long long k0 = ((unsigned long long)f2key(fmaf(-2.0f, a0, wn0)) << 32) | (unsigned)(c0 + 0);
        unsigned long long k1 = ((unsigned long long)f2key(fmaf(-2.0f, a1, wn1)) << 32) | (unsigned)(c0 + 1);
        unsigned long long k2 = ((unsigned long long)f2key(fmaf(-2.0f, a2, wn2)) << 32) | (unsigned)(c0 + 2);
        unsigned long long k3 = ((unsigned long long)f2key(fmaf(-2.0f, a3, wn3)) << 32) | (unsigned)(c0 + 3);
        unsigned long long b01 = k0 < k1 ? k0 : k1;
        unsigned long long b23 = k2 < k3 ? k2 : k3;
        return b01 < b23 ? b01 : b23;
    };

    int i = 0;
    for (; i + 2 <= n; i += 2) {
        const int r0 = list[i], r1 = list[i + 1];
        float4 x0 = *(const float4*)&lat[(size_t)r0 * C_DIM + lane * 4];
        float4 x1 = *(const float4*)&lat[(size_t)r1 * C_DIM + lane * 4];
        float d00 = dot4(x0, wv0), d01 = dot4(x0, wv1), d02 = dot4(x0, wv2), d03 = dot4(x0, wv3);
        float d10 = dot4(x1, wv0), d11 = dot4(x1, wv1), d12 = dot4(x1, wv2), d13 = dot4(x1, wv3);
        #pragma unroll
        for (int m = 1; m < 64; m <<= 1) {
            d00 += __shfl_xor(d00, m, 64); d01 += __shfl_xor(d01, m, 64);
            d02 += __shfl_xor(d02, m, 64); d03 += __shfl_xor(d03, m, 64);
            d10 += __shfl_xor(d10, m, 64); d11 += __shfl_xor(d11, m, 64);
            d12 += __shfl_xor(d12, m, 64); d13 += __shfl_xor(d13, m, 64);
        }
        if (lane == 0) {
            unsigned long long b0 = best4(d00, d01, d02, d03);
            unsigned long long b1 = best4(d10, d11, d12, d13);
            if (b0 < keys[r0]) atomicMin(&keys[r0], b0);
            if (b1 < keys[r1]) atomicMin(&keys[r1], b1);
        }
    }
    if (i < n) {
        const int r0 = list[i];
        float4 x0 = *(const float4*)&lat[(size_t)r0 * C_DIM + lane * 4];
        float d00 = dot4(x0, wv0), d01 = dot4(x0, wv1), d02 = dot4(x0, wv2), d03 = dot4(x0, wv3);
        #pragma unroll
        for (int m = 1; m < 64; m <<= 1) {
            d00 += __shfl_xor(d00, m, 64); d01 += __shfl_xor(d01, m, 64);
            d02 += __shfl_xor(d02, m, 64); d03 += __shfl_xor(d03, m, 64);
        }
        if (lane == 0) {
            unsigned long long b0 = best4(d00, d01, d02, d03);
            if (b0 < keys[r0]) atomicMin(&keys[r0], b0);
        }
    }
}

// ---------------- finalize: 8 rows/block (2048 blocks) ----------------
extern "C" __global__ void finalize_kernel(const float* __restrict__ lat,
                                           const float* __restrict__ cbk,
                                           const float* __restrict__ noise,
                                           const unsigned long long* __restrict__ keys,
                                           float* __restrict__ out,
                                           float* __restrict__ lpart) {
    const int g = threadIdx.x >> 5;
    const int l = threadIdx.x & 31;
    const int row = blockIdx.x * 8 + g;
    const unsigned long long p = keys[row];
    const int id = (int)(unsigned)(p & 0xFFFFFFFFull);
    const int off = (int)rintf(noise[row] * 0.5f);
    int idn = id + off;
    idn = idn < 0 ? 0 : (idn > K_CODES - 1 ? K_CODES - 1 : idn);
    const float4* latp = (const float4*)&lat[(size_t)row * C_DIM];
    const float4* qdp  = (const float4*)&cbk[(size_t)id  * C_DIM];
    const float4* qnp  = (const float4*)&cbk[(size_t)idn * C_DIM];
    float4* stp = (float4*)&out[(size_t)row * C_DIM];
    float t = 0.0f;
    #pragma unroll
    for (int j = 0; j < 2; ++j) {
        const int e = l + j * 32;
        float4 x  = latp[e];
        float4 qd = qdp[e];
        float4 qn = qnp[e];
        float4 st = {x.x + (qn.x - x.x), x.y + (qn.y - x.y),
                     x.z + (qn.z - x.z), x.w + (qn.w - x.w)};
        stp[e] = st;
        float d1, d2;
        d1 = x.x - qd.x; d2 = qn.x - x.x; t += 0.25f * d1 * d1 + d2 * d2;
        d1 = x.y - qd.y; d2 = qn.y - x.y; t += 0.25f * d1 * d1 + d2 * d2;
        d1 = x.z - qd.z; d2 = qn.z - x.z; t += 0.25f * d1 * d1 + d2 * d2;
        d1 = x.w - qd.w; d2 = qn.w - x.w; t += 0.25f * d1 * d1 + d2 * d2;
    }
    t *= (1.0f / 4194304.0f);
    #pragma unroll
    for (int m = 1; m < 32; m <<= 1) t += __shfl_xor(t, m, 64);
    __shared__ float red[8];
    if (l == 0) {
        red[g] = t;
        out[(size_t)N_ROWS * C_DIM + 1 + row] = (float)idn;
    }
    __syncthreads();
    if (threadIdx.x == 0) {
        float s = red[0] + red[1] + red[2] + red[3] + red[4] + red[5] + red[6] + red[7];
        atomicAdd(&lpart[blockIdx.x & 1023], s);
    }
}

extern "C" __global__ void loss_reduce_kernel(const float* __restrict__ lpart,
                                              float* __restrict__ out) {
    const int t = threadIdx.x;
    float s = lpart[t] + lpart[t + 256] + lpart[t + 512] + lpart[t + 768];
    #pragma unroll
    for (int m = 32; m; m >>= 1) s += __shfl_xor(s, m, 64);
    __shared__ float red[4];
    if ((t & 63) == 0) red[t >> 6] = s;
    __syncthreads();
    if (t == 0) out[(size_t)N_ROWS * C_DIM] = red[0] + red[1] + red[2] + red[3];
}

extern "C" void kernel_launch(void* const* d_in, const int* in_sizes, int n_in,
                              void* d_out, int out_size, void* d_ws, size_t ws_size,
                              hipStream_t stream) {
    const float* lat   = (const float*)d_in[0];
    const float* cbk   = (const float*)d_in[1];
    const float* noise = (const float*)d_in[2];
    float* out = (float*)d_out;

    char* ws = (char*)d_ws;
    unsigned short* xh = (unsigned short*)(ws);                      //  8 MB
    unsigned short* xl = (unsigned short*)(ws + 8388608);            //  8 MB
    unsigned short* wh = (unsigned short*)(ws + 16777216);           //  4 MB
    unsigned short* wl = (unsigned short*)(ws + 20971520);           //  4 MB
    float* wnorm       = (float*)(ws + 25165824);                    // 32 KB
    unsigned long long* keys = (unsigned long long*)(ws + 25198592); // 128 KB  \ one
    unsigned* keys2    = (unsigned*)(ws + 25329664);                 // 64 KB   / 0xFF memset
    int* list          = (int*)(ws + 25395200);                      // 64 KB
    float* lpart       = (float*)(ws + 25460736);                    // 4 KB    \ one
    int* count         = (int*)(ws + 25464832);                      // 4 B     / 0 memset

    hipMemsetAsync(keys, 0xFF, 192 * 1024, stream);                  // keys + keys2
    hipMemsetAsync(lpart, 0, 4096 + 4, stream);                      // lpart + count

    prep_kernel <<<2048, 256, 0, stream>>>(lat, xh, xl);
    prepw_kernel<<<1024, 256, 0, stream>>>(cbk, wh, wl, wnorm);
    pass1_kernel<<<1024, 256, 0, stream>>>(xh, xl, wh, wl, wnorm, keys, keys2);
    flag_kernel <<<N_ROWS / 256, 256, 0, stream>>>(keys, keys2, list, count);
    rerank_kernel<<<512, 256, 0, stream>>>(lat, cbk, wnorm, list, count, keys);
    finalize_kernel<<<N_ROWS / 8, 256, 0, stream>>>(lat, cbk, noise, keys, out, lpart);
    loss_reduce_kernel<<<1, 256, 0, stream>>>(lpart, out);
}